// Round 6
// baseline (356.965 us; speedup 1.0000x reference)
//
#include <hip/hip_runtime.h>

#define SLOPE 0.22916666666666666f  // (1/8 + 1/3) / 2
#define ALONE_CAP 2048              // expected alone nodes ~2.3

typedef __attribute__((ext_vector_type(8))) short bfrag;   // 8 x bf16 bits
typedef __attribute__((ext_vector_type(4))) float ffrag;   // 4 x f32 acc

__device__ __forceinline__ unsigned short rne16(float f) {
    unsigned u = __float_as_uint(f);
    return (unsigned short)((u + 0x7FFFu + ((u >> 16) & 1u)) >> 16);
}
__device__ __forceinline__ float bf2f(unsigned short h) {
    return __uint_as_float(((unsigned)h) << 16);
}
// interleaved split word: hi bf16 in [31:16], lo bf16 in [15:0]
__device__ __forceinline__ unsigned packsplit(float f) {
    unsigned short hi = rne16(f);
    unsigned short lo = rne16(f - bf2f(hi));
    return ((unsigned)hi << 16) | lo;
}
__device__ __forceinline__ float recon(unsigned u) {
    return __uint_as_float(u & 0xFFFF0000u) + __uint_as_float(u << 16);
}
__device__ __forceinline__ float4 recon4(uint4 u) {
    return make_float4(recon(u.x), recon(u.y), recon(u.z), recon(u.w));
}

// ---------------------------------------------------------------- prep
// Fused: [0,eb) count in-degrees; [eb,eb+cb) split ent -> interleaved Esp;
// [eb+cb, +32) pack W into MFMA B-fragment order (hi/lo planes).
// B layout (fragment-major, per plane of 16384 shorts):
//   plane[kc*4096 + ct*512 + (quad*16 + l16)*8 + j] = bf16(W[kc*32+quad*8+j][ct*16+l16])
// so a wave's ds_read_b128 for column-tile ct is contiguous 1KB (lane*16B).
__global__ __launch_bounds__(256) void prep_kernel(
    const int* __restrict__ dst, int* __restrict__ deg, int e, int eb,
    const float* __restrict__ ent, unsigned* __restrict__ Esp,
    int total4, int cb,
    const float* __restrict__ Wn, const float* __restrict__ Wl,
    ushort* __restrict__ packW) {
    int b = blockIdx.x;
    if (b < eb) {
        int i = b * 256 + threadIdx.x;
        if (i < e) atomicAdd(&deg[dst[i]], 1);
    } else if (b < eb + cb) {
        int i = (b - eb) * 256 + threadIdx.x;
        if (i >= total4) return;
        float4 v = ((const float4*)ent)[i];
        uint4 w;
        w.x = packsplit(v.x); w.y = packsplit(v.y);
        w.z = packsplit(v.z); w.w = packsplit(v.w);
        ((uint4*)Esp)[i] = w;
    } else {
        int t = (b - eb - cb) * 256 + threadIdx.x;
        if (t >= 4 * 4 * 128 * 4) return;
        int quad = t & 3;
        int nn   = (t >> 2) & 127;
        int kc   = (t >> 9) & 3;
        int mat  = t >> 11;   // 0=Wn L0, 1=Wl L0, 2=Wn L1, 3=Wl L1
        const float* W = ((mat & 1) ? Wl : Wn) + (mat >> 1) * 16384;
        ushort* oh = packW + mat * 32768;
        ushort* ol = oh + 16384;
        int obase = kc * 4096 + (nn >> 4) * 512 + (quad * 16 + (nn & 15)) * 8;
        #pragma unroll
        for (int j = 0; j < 8; ++j) {
            float w = W[(kc * 32 + quad * 8 + j) * 128 + nn];
            unsigned short hi = rne16(w);
            oh[obase + j] = hi;
            ol[obase + j] = rne16(w - bf2f(hi));
        }
    }
}

// --- scan: partial block sums, then finalize (aux prefix inlined) ---------
__global__ __launch_bounds__(256) void scan_partial_kernel(const int* __restrict__ deg,
                                                           int* __restrict__ partial, int n) {
    __shared__ int wsum[4];
    int base = blockIdx.x * 1024;
    int t = threadIdx.x;
    int s = 0;
    #pragma unroll
    for (int j = 0; j < 4; ++j) {
        int i = base + t + 256 * j;
        if (i < n) s += deg[i];
    }
    #pragma unroll
    for (int off = 1; off < 64; off <<= 1) s += __shfl_xor(s, off, 64);
    if ((t & 63) == 0) wsum[t >> 6] = s;
    __syncthreads();
    if (t == 0) partial[blockIdx.x] = wsum[0] + wsum[1] + wsum[2] + wsum[3];
}

// exclusive scan finalize (computes own block base from partial[]) +
// alone-node detection (deg==0). Requires nparts <= 64.
__global__ __launch_bounds__(256) void scan_final_kernel(const int* __restrict__ deg,
                                                         const int* __restrict__ partial,
                                                         int* __restrict__ row_off,
                                                         int* __restrict__ alone_list,
                                                         int* __restrict__ alone_count, int n) {
    __shared__ int wsum[4];
    __shared__ int sbase;
    int bid = blockIdx.x;
    int t = threadIdx.x, lane = t & 63, wid = t >> 6;
    if (wid == 0) {
        int v = (lane < bid) ? partial[lane] : 0;
        #pragma unroll
        for (int off = 1; off < 64; off <<= 1) v += __shfl_xor(v, off, 64);
        if (lane == 0) sbase = v;
    }
    int base = bid * 1024;
    int i0 = base + t * 4;
    int v0 = (i0 + 0 < n) ? deg[i0 + 0] : 0;
    int v1 = (i0 + 1 < n) ? deg[i0 + 1] : 0;
    int v2 = (i0 + 2 < n) ? deg[i0 + 2] : 0;
    int v3 = (i0 + 3 < n) ? deg[i0 + 3] : 0;
    int s = v0 + v1 + v2 + v3;
    int x = s;
    #pragma unroll
    for (int off = 1; off < 64; off <<= 1) {
        int y = __shfl_up(x, off, 64);
        if (lane >= off) x += y;
    }
    if (lane == 63) wsum[wid] = x;
    __syncthreads();
    int wbase = 0;
    #pragma unroll
    for (int w = 0; w < 4; ++w) { int ws = wsum[w]; if (w < wid) wbase += ws; }
    int p = sbase + wbase + x - s;
    if (i0 + 0 <= n) row_off[i0 + 0] = p;
    p += v0;
    if (i0 + 1 <= n) row_off[i0 + 1] = p;
    p += v1;
    if (i0 + 2 <= n) row_off[i0 + 2] = p;
    p += v2;
    if (i0 + 3 <= n) row_off[i0 + 3] = p;
    if (i0 + 0 < n && v0 == 0) { int q = atomicAdd(alone_count, 1); if (q < ALONE_CAP) alone_list[q] = i0; }
    if (i0 + 1 < n && v1 == 0) { int q = atomicAdd(alone_count, 1); if (q < ALONE_CAP) alone_list[q] = i0 + 1; }
    if (i0 + 2 < n && v2 == 0) { int q = atomicAdd(alone_count, 1); if (q < ALONE_CAP) alone_list[q] = i0 + 2; }
    if (i0 + 3 < n && v3 == 0) { int q = atomicAdd(alone_count, 1); if (q < ALONE_CAP) alone_list[q] = i0 + 3; }
}

// edges packed as uint: src | (ety << 16). Valid: N_ENTS=50000<2^16, N_RELS=200.
__global__ __launch_bounds__(256) void scatter_kernel(
    const int* __restrict__ src, const int* __restrict__ dst,
    const int* __restrict__ ety, const int* __restrict__ row_off,
    int* __restrict__ cursor, unsigned* __restrict__ edges, int e) {
    int i = blockIdx.x * 256 + threadIdx.x;
    if (i < e) {
        int v = dst[i];
        int pos = row_off[v] + atomicAdd(&cursor[v], 1);
        edges[pos] = (unsigned)src[i] | ((unsigned)ety[i] << 16);
    }
}

// --------------------------------------------------- fused per-layer kernel
// Block = 256 thr = 4 waves owns 64 output rows. Phase 1 (gather): wave w
// accumulates its 16 nodes' edges in fp32 (half-wave/edge, 8 in flight) and
// writes S rows (x norm) to LDS [64][132] f32 (+4 pad -> 2-way-free banks).
// Phase 2 (GEMM): v5 structure -- B double-buffered in LDS (named scalars,
// no spill), steps 0-3 take A from LDS-resident fp32 S (split to bf16 hi/lo
// in regs; numerically identical to old packsplit path), steps 4-7 from the
// register-hoisted own-row H slab. Kills the Ssp 51MB/layer round-trip and
// gemm's A-side global latency chain. LDS 65KB -> 2 blocks/CU.
// SPLIT=0: gather from fp32 gf (layer 0: ent). SPLIT=1: gather from split gs.
// Alias-safe (layer0 Osp=Esp): each block writes only its own 64 Esp rows,
// reads Esp only for those same rows (H hoist, consumed before epilogue).
template <int SPLIT>
__global__ __launch_bounds__(256, 2) void fused_layer_kernel(
    const float* __restrict__ gf, const unsigned* __restrict__ gs,
    const unsigned* __restrict__ Hsp,
    const float* __restrict__ rel, const float* __restrict__ norm,
    const int* __restrict__ row_off, const unsigned* __restrict__ edges,
    const ushort* __restrict__ Pnh, const ushort* __restrict__ Pnl,
    const ushort* __restrict__ Plh, const ushort* __restrict__ Pll,
    float* out, unsigned* Osp, int n) {
    __shared__ float Sld[64][132];          // 33.8 KB, +4 pad
    __shared__ ushort ldsB[2][2][4096];     // 32 KB B double-buffer

    const int tid = threadIdx.x;
    const int wave = tid >> 6, lane = tid & 63;
    const int quad = lane >> 4, l16 = lane & 15;
    const int row_base = blockIdx.x * 64 + wave * 16;

    int r0c = row_base + l16;
    if (r0c > n - 1) r0c = n - 1;
    const size_t arow = (size_t)r0c * 128;
    const int q8 = quad * 8;

    // ---- prologue: hoist own-row H slab (named, static) + stage B slice 0
    uint4 h00 = *(const uint4*)(Hsp + arow + 0 * 32 + q8);
    uint4 h01 = *(const uint4*)(Hsp + arow + 0 * 32 + q8 + 4);
    uint4 h10 = *(const uint4*)(Hsp + arow + 1 * 32 + q8);
    uint4 h11 = *(const uint4*)(Hsp + arow + 1 * 32 + q8 + 4);
    uint4 h20 = *(const uint4*)(Hsp + arow + 2 * 32 + q8);
    uint4 h21 = *(const uint4*)(Hsp + arow + 2 * 32 + q8 + 4);
    uint4 h30 = *(const uint4*)(Hsp + arow + 3 * 32 + q8);
    uint4 h31 = *(const uint4*)(Hsp + arow + 3 * 32 + q8 + 4);
    {
        uint4 t0 = *(const uint4*)(Pnh + tid * 8);
        uint4 t1 = *(const uint4*)(Pnh + 2048 + tid * 8);
        uint4 t2 = *(const uint4*)(Pnl + tid * 8);
        uint4 t3 = *(const uint4*)(Pnl + 2048 + tid * 8);
        *(uint4*)&ldsB[0][0][tid * 8] = t0;
        *(uint4*)&ldsB[0][0][2048 + tid * 8] = t1;
        *(uint4*)&ldsB[0][1][tid * 8] = t2;
        *(uint4*)&ldsB[0][1][2048 + tid * 8] = t3;
    }

    // ---- phase 1: gather own 16 nodes' S rows into LDS (fp32)
    {
        const int half = lane >> 5;
        const int c4 = (lane & 31) * 4;
        #pragma unroll 1
        for (int i = 0; i < 16; ++i) {
            const int v = row_base + i;
            float4 acc = make_float4(0.f, 0.f, 0.f, 0.f);
            float nm = 0.f;
            if (v < n) {
                nm = norm[v];
                int s0 = row_off[v], s1 = row_off[v + 1];
                int e = s0;
                for (; e + 7 < s1; e += 8) {
                    unsigned q0 = edges[e + half];
                    unsigned q1 = edges[e + 2 + half];
                    unsigned q2 = edges[e + 4 + half];
                    unsigned q3 = edges[e + 6 + half];
                    float4 h0, h1, h2, h3;
                    if (SPLIT) {
                        h0 = recon4(*(const uint4*)&gs[(size_t)(q0 & 0xFFFFu) * 128 + c4]);
                        h1 = recon4(*(const uint4*)&gs[(size_t)(q1 & 0xFFFFu) * 128 + c4]);
                        h2 = recon4(*(const uint4*)&gs[(size_t)(q2 & 0xFFFFu) * 128 + c4]);
                        h3 = recon4(*(const uint4*)&gs[(size_t)(q3 & 0xFFFFu) * 128 + c4]);
                    } else {
                        h0 = *(const float4*)&gf[(size_t)(q0 & 0xFFFFu) * 128 + c4];
                        h1 = *(const float4*)&gf[(size_t)(q1 & 0xFFFFu) * 128 + c4];
                        h2 = *(const float4*)&gf[(size_t)(q2 & 0xFFFFu) * 128 + c4];
                        h3 = *(const float4*)&gf[(size_t)(q3 & 0xFFFFu) * 128 + c4];
                    }
                    float4 r0 = *(const float4*)&rel[(size_t)(q0 >> 16) * 128 + c4];
                    float4 r1 = *(const float4*)&rel[(size_t)(q1 >> 16) * 128 + c4];
                    float4 r2 = *(const float4*)&rel[(size_t)(q2 >> 16) * 128 + c4];
                    float4 r3 = *(const float4*)&rel[(size_t)(q3 >> 16) * 128 + c4];
                    acc.x += ((h0.x + r0.x) + (h1.x + r1.x)) + ((h2.x + r2.x) + (h3.x + r3.x));
                    acc.y += ((h0.y + r0.y) + (h1.y + r1.y)) + ((h2.y + r2.y) + (h3.y + r3.y));
                    acc.z += ((h0.z + r0.z) + (h1.z + r1.z)) + ((h2.z + r2.z) + (h3.z + r3.z));
                    acc.w += ((h0.w + r0.w) + (h1.w + r1.w)) + ((h2.w + r2.w) + (h3.w + r3.w));
                }
                for (; e + 1 < s1; e += 2) {
                    unsigned q0 = edges[e + half];
                    float4 h0 = SPLIT ? recon4(*(const uint4*)&gs[(size_t)(q0 & 0xFFFFu) * 128 + c4])
                                      : *(const float4*)&gf[(size_t)(q0 & 0xFFFFu) * 128 + c4];
                    float4 r0 = *(const float4*)&rel[(size_t)(q0 >> 16) * 128 + c4];
                    acc.x += h0.x + r0.x; acc.y += h0.y + r0.y;
                    acc.z += h0.z + r0.z; acc.w += h0.w + r0.w;
                }
                if (e < s1 && half == 0) {
                    unsigned q0 = edges[e];
                    float4 h0 = SPLIT ? recon4(*(const uint4*)&gs[(size_t)(q0 & 0xFFFFu) * 128 + c4])
                                      : *(const float4*)&gf[(size_t)(q0 & 0xFFFFu) * 128 + c4];
                    float4 r0 = *(const float4*)&rel[(size_t)(q0 >> 16) * 128 + c4];
                    acc.x += h0.x + r0.x; acc.y += h0.y + r0.y;
                    acc.z += h0.z + r0.z; acc.w += h0.w + r0.w;
                }
            }
            acc.x += __shfl_xor(acc.x, 32, 64);
            acc.y += __shfl_xor(acc.y, 32, 64);
            acc.z += __shfl_xor(acc.z, 32, 64);
            acc.w += __shfl_xor(acc.w, 32, 64);
            if (half == 0) {
                *(float4*)&Sld[wave * 16 + i][c4] =
                    make_float4(acc.x * nm, acc.y * nm, acc.z * nm, acc.w * nm);
            }
        }
    }
    __syncthreads();  // S visible + B slice 0 staged

    ffrag acc[8];
    #pragma unroll
    for (int ct = 0; ct < 8; ++ct) acc[ct] = (ffrag)0.f;

    // Common step body pieces -------------------------------------------------
#define GSTAGE(NPH, NPL, NKC)                                                    \
        s0 = *(const uint4*)((NPH) + (NKC) * 4096 + tid * 8);                    \
        s1 = *(const uint4*)((NPH) + (NKC) * 4096 + 2048 + tid * 8);             \
        s2 = *(const uint4*)((NPL) + (NKC) * 4096 + tid * 8);                    \
        s3 = *(const uint4*)((NPL) + (NKC) * 4096 + 2048 + tid * 8);

#define GCOMPUTE(IT)                                                             \
        bfrag bh[8], bl[8];                                                      \
        _Pragma("unroll")                                                        \
        for (int ct = 0; ct < 8; ++ct) {                                         \
            bh[ct] = *(const bfrag*)&ldsB[(IT) & 1][0][ct * 512 + lane * 8];     \
            bl[ct] = *(const bfrag*)&ldsB[(IT) & 1][1][ct * 512 + lane * 8];     \
        }                                                                        \
        _Pragma("unroll")                                                        \
        for (int ct = 0; ct < 8; ++ct)                                           \
            acc[ct] = __builtin_amdgcn_mfma_f32_16x16x32_bf16(ah, bh[ct], acc[ct], 0, 0, 0); \
        _Pragma("unroll")                                                        \
        for (int ct = 0; ct < 8; ++ct)                                           \
            acc[ct] = __builtin_amdgcn_mfma_f32_16x16x32_bf16(ah, bl[ct], acc[ct], 0, 0, 0); \
        _Pragma("unroll")                                                        \
        for (int ct = 0; ct < 8; ++ct)                                           \
            acc[ct] = __builtin_amdgcn_mfma_f32_16x16x32_bf16(al, bh[ct], acc[ct], 0, 0, 0);

#define GFINISH(IT, HAVE)                                                        \
        if (HAVE) {                                                              \
            *(uint4*)&ldsB[((IT) + 1) & 1][0][tid * 8] = s0;                     \
            *(uint4*)&ldsB[((IT) + 1) & 1][0][2048 + tid * 8] = s1;              \
            *(uint4*)&ldsB[((IT) + 1) & 1][1][tid * 8] = s2;                     \
            *(uint4*)&ldsB[((IT) + 1) & 1][1][2048 + tid * 8] = s3;              \
            __syncthreads();                                                     \
        }

    // Steps 0-3: A from LDS fp32 S (split in regs)
#define GSTEP_S(IT, KC, NPH, NPL, NKC, HAVE)                                     \
    {                                                                            \
        uint4 s0, s1, s2, s3;                                                    \
        if (HAVE) { GSTAGE(NPH, NPL, NKC) }                                      \
        float4 f0 = *(const float4*)&Sld[wave * 16 + l16][(KC) * 32 + q8];       \
        float4 f1 = *(const float4*)&Sld[wave * 16 + l16][(KC) * 32 + q8 + 4];   \
        bfrag ah, al;                                                            \
        _Pragma("unroll")                                                        \
        for (int j = 0; j < 4; ++j) {                                            \
            float fa = ((const float*)&f0)[j];                                   \
            float fb = ((const float*)&f1)[j];                                   \
            unsigned short ha = rne16(fa);                                       \
            unsigned short hb = rne16(fb);                                       \
            ah[j]     = (short)ha; al[j]     = (short)rne16(fa - bf2f(ha));      \
            ah[j + 4] = (short)hb; al[j + 4] = (short)rne16(fb - bf2f(hb));      \
        }                                                                        \
        GCOMPUTE(IT)                                                             \
        GFINISH(IT, HAVE)                                                        \
    }

    // Steps 4-7: A from hoisted H registers (interleaved split)
#define GSTEP_H(IT, A0, A1, NPH, NPL, NKC, HAVE)                                 \
    {                                                                            \
        uint4 s0, s1, s2, s3;                                                    \
        if (HAVE) { GSTAGE(NPH, NPL, NKC) }                                      \
        bfrag ah, al;                                                            \
        _Pragma("unroll")                                                        \
        for (int j = 0; j < 4; ++j) {                                            \
            unsigned u0 = ((const unsigned*)&(A0))[j];                           \
            unsigned u1 = ((const unsigned*)&(A1))[j];                           \
            ah[j]     = (short)(u0 >> 16); al[j]     = (short)(u0 & 0xFFFFu);    \
            ah[j + 4] = (short)(u1 >> 16); al[j + 4] = (short)(u1 & 0xFFFFu);    \
        }                                                                        \
        GCOMPUTE(IT)                                                             \
        GFINISH(IT, HAVE)                                                        \
    }

    GSTEP_S(0, 0, Pnh, Pnl, 1, 1)
    GSTEP_S(1, 1, Pnh, Pnl, 2, 1)
    GSTEP_S(2, 2, Pnh, Pnl, 3, 1)
    GSTEP_S(3, 3, Plh, Pll, 0, 1)
    GSTEP_H(4, h00, h01, Plh, Pll, 1, 1)
    GSTEP_H(5, h10, h11, Plh, Pll, 2, 1)
    GSTEP_H(6, h20, h21, Plh, Pll, 3, 1)
    GSTEP_H(7, h30, h31, Plh, Pll, 0, 0)
#undef GSTEP_S
#undef GSTEP_H
#undef GSTAGE
#undef GCOMPUTE
#undef GFINISH

    #pragma unroll
    for (int ct = 0; ct < 8; ++ct) {
        #pragma unroll
        for (int rg = 0; rg < 4; ++rg) {
            int r = row_base + quad * 4 + rg;
            if (r < n) {
                int c = ct * 16 + l16;
                float v = acc[ct][rg];
                v = v >= 0.f ? v : v * SLOPE;
                if (out) out[(size_t)r * 128 + c] = v;
                if (Osp) Osp[(size_t)r * 128 + c] = packsplit(v);
            }
        }
    }
}

// Alone nodes: o = leaky(hrow @ Wa).
// Layer 0 (by_node=1): hrow = ent[v]; writes Osp (h1 split) + asave fp32.
// Layer 1 (by_node=0): hrow = asave[i]; writes out fp32.
__global__ __launch_bounds__(128) void fixup_kernel(
    const float* __restrict__ Hrows, int by_node,
    const float* __restrict__ Wa,
    const int* __restrict__ alone_list, const int* __restrict__ alone_count,
    float* out, unsigned* Osp, float* asave) {
    int cnt = *alone_count;
    if (cnt > ALONE_CAP) cnt = ALONE_CAP;
    int t = threadIdx.x;
    for (int i = blockIdx.x; i < cnt; i += gridDim.x) {
        int v = alone_list[i];
        const float* hrow = Hrows + (size_t)(by_node ? v : i) * 128;
        float acc = 0.f;
        for (int k = 0; k < 128; ++k)
            acc += hrow[k] * Wa[k * 128 + t];
        float o = acc >= 0.f ? acc : acc * SLOPE;
        if (out) out[(size_t)v * 128 + t] = o;
        if (Osp) Osp[(size_t)v * 128 + t] = packsplit(o);
        if (asave) asave[(size_t)i * 128 + t] = o;
    }
}

extern "C" void kernel_launch(void* const* d_in, const int* in_sizes, int n_in,
                              void* d_out, int out_size, void* d_ws, size_t ws_size,
                              hipStream_t stream) {
    const float* ent  = (const float*)d_in[0];
    const float* rel  = (const float*)d_in[1];
    const float* norm = (const float*)d_in[2];
    const float* Wn   = (const float*)d_in[3];
    const float* Wl   = (const float*)d_in[4];
    const float* Wa   = (const float*)d_in[5];
    const int*   src  = (const int*)d_in[6];
    const int*   dst  = (const int*)d_in[7];
    const int*   ety  = (const int*)d_in[8];
    float* out = (float*)d_out;

    const int n = in_sizes[2];   // 50000
    const int e = in_sizes[7];   // 500000

    // workspace layout
    char* ws = (char*)d_ws;
    int* deg         = (int*)ws;          // n
    int* cursor      = deg + n;           // n
    int* alone_count = cursor + n;        // 1
    size_t zbytes = (size_t)(2 * n + 1) * sizeof(int);
    size_t p = (zbytes + 255) & ~(size_t)255;
    int* row_off = (int*)(ws + p);        // n+1
    p += (((size_t)(n + 1) * 4) + 255) & ~(size_t)255;
    int* partial = (int*)(ws + p);        // <=64
    p += 256;
    int* alone_list = (int*)(ws + p);     // ALONE_CAP
    p += (((size_t)ALONE_CAP * 4) + 255) & ~(size_t)255;
    float* asave = (float*)(ws + p);      // ALONE_CAP*128 f32 (1 MB)
    p += (((size_t)ALONE_CAP * 128 * 4) + 255) & ~(size_t)255;
    unsigned* edges = (unsigned*)(ws + p);// e packed (2 MB)
    p += (((size_t)e * 4) + 255) & ~(size_t)255;
    unsigned* Esp = (unsigned*)(ws + p);  // ent split; becomes h1 split (25.6 MB)
    p += (((size_t)n * 128 * 4) + 255) & ~(size_t)255;
    ushort* packW = (ushort*)(ws + p);    // 4 mats x (hi16K + lo16K) (256 KB)
    p += 4 * 32768 * 2;

    const int eb = (e + 255) / 256;             // 1954
    const int cb = (n * 32 + 255) / 256;        // 6250 (float4 units)
    const int nparts = (n + 1023) / 1024;       // 49 (<=64 required)
    const int gb = (n + 63) / 64;               // 782

    hipMemsetAsync(ws, 0, zbytes, stream);
    prep_kernel<<<eb + cb + 32, 256, 0, stream>>>(dst, deg, e, eb,
                                                  ent, Esp, n * 32, cb,
                                                  Wn, Wl, packW);
    scan_partial_kernel<<<nparts, 256, 0, stream>>>(deg, partial, n);
    scan_final_kernel<<<nparts, 256, 0, stream>>>(deg, partial, row_off,
                                                  alone_list, alone_count, n);
    scatter_kernel<<<eb, 256, 0, stream>>>(src, dst, ety, row_off, cursor, edges, e);

    // layer 0: gather from ent (fp32), H = Esp (ent split); writes Esp (h1 split)
    fused_layer_kernel<0><<<gb, 256, 0, stream>>>(
        ent, nullptr, Esp, rel, norm, row_off, edges,
        packW, packW + 16384, packW + 32768, packW + 49152,
        nullptr, Esp, n);
    fixup_kernel<<<16, 128, 0, stream>>>(ent, 1, Wa, alone_list, alone_count,
                                         nullptr, Esp, asave);

    // layer 1: gather from Esp (h1 split), H = Esp; writes out fp32
    fused_layer_kernel<1><<<gb, 256, 0, stream>>>(
        nullptr, Esp, Esp, rel, norm, row_off, edges,
        packW + 65536, packW + 81920, packW + 98304, packW + 114688,
        out, nullptr, n);
    fixup_kernel<<<16, 128, 0, stream>>>(asave, 0, Wa + 16384, alone_list, alone_count,
                                         out, nullptr, nullptr);
}

// Round 7
// 354.838 us; speedup vs baseline: 1.0060x; 1.0060x over previous
//
#include <hip/hip_runtime.h>

#define SLOPE 0.22916666666666666f  // (1/8 + 1/3) / 2
#define ALONE_CAP 2048              // expected alone nodes ~2.3

typedef __attribute__((ext_vector_type(8))) short bfrag;   // 8 x bf16 bits
typedef __attribute__((ext_vector_type(4))) float ffrag;   // 4 x f32 acc

__device__ __forceinline__ unsigned short rne16(float f) {
    unsigned u = __float_as_uint(f);
    return (unsigned short)((u + 0x7FFFu + ((u >> 16) & 1u)) >> 16);
}
__device__ __forceinline__ float bf2f(unsigned short h) {
    return __uint_as_float(((unsigned)h) << 16);
}
// interleaved split word: hi bf16 in [31:16], lo bf16 in [15:0]
__device__ __forceinline__ unsigned packsplit(float f) {
    unsigned short hi = rne16(f);
    unsigned short lo = rne16(f - bf2f(hi));
    return ((unsigned)hi << 16) | lo;
}
__device__ __forceinline__ float recon(unsigned u) {
    return __uint_as_float(u & 0xFFFF0000u) + __uint_as_float(u << 16);
}
__device__ __forceinline__ float4 recon4(uint4 u) {
    return make_float4(recon(u.x), recon(u.y), recon(u.z), recon(u.w));
}

// ---------------------------------------------------------------- prep
// Fused: [0,eb) count in-degrees; [eb,eb+cb) split ent -> interleaved Esp;
// [eb+cb, +32) pack W into MFMA B-fragment order (hi/lo planes).
// B layout (fragment-major, per plane of 16384 shorts):
//   plane[kc*4096 + ct*512 + (quad*16 + l16)*8 + j] = bf16(W[kc*32+quad*8+j][ct*16+l16])
// so a wave's ds_read_b128 for column-tile ct is contiguous 1KB (lane*16B).
__global__ __launch_bounds__(256) void prep_kernel(
    const int* __restrict__ dst, int* __restrict__ deg, int e, int eb,
    const float* __restrict__ ent, unsigned* __restrict__ Esp,
    int total4, int cb,
    const float* __restrict__ Wn, const float* __restrict__ Wl,
    ushort* __restrict__ packW) {
    int b = blockIdx.x;
    if (b < eb) {
        int i = b * 256 + threadIdx.x;
        if (i < e) atomicAdd(&deg[dst[i]], 1);
    } else if (b < eb + cb) {
        int i = (b - eb) * 256 + threadIdx.x;
        if (i >= total4) return;
        float4 v = ((const float4*)ent)[i];
        uint4 w;
        w.x = packsplit(v.x); w.y = packsplit(v.y);
        w.z = packsplit(v.z); w.w = packsplit(v.w);
        ((uint4*)Esp)[i] = w;
    } else {
        int t = (b - eb - cb) * 256 + threadIdx.x;
        if (t >= 4 * 4 * 128 * 4) return;
        int quad = t & 3;
        int nn   = (t >> 2) & 127;
        int kc   = (t >> 9) & 3;
        int mat  = t >> 11;   // 0=Wn L0, 1=Wl L0, 2=Wn L1, 3=Wl L1
        const float* W = ((mat & 1) ? Wl : Wn) + (mat >> 1) * 16384;
        ushort* oh = packW + mat * 32768;
        ushort* ol = oh + 16384;
        int obase = kc * 4096 + (nn >> 4) * 512 + (quad * 16 + (nn & 15)) * 8;
        #pragma unroll
        for (int j = 0; j < 8; ++j) {
            float w = W[(kc * 32 + quad * 8 + j) * 128 + nn];
            unsigned short hi = rne16(w);
            oh[obase + j] = hi;
            ol[obase + j] = rne16(w - bf2f(hi));
        }
    }
}

// --- scan: partial block sums, then finalize (aux prefix inlined) ---------
__global__ __launch_bounds__(256) void scan_partial_kernel(const int* __restrict__ deg,
                                                           int* __restrict__ partial, int n) {
    __shared__ int wsum[4];
    int base = blockIdx.x * 1024;
    int t = threadIdx.x;
    int s = 0;
    #pragma unroll
    for (int j = 0; j < 4; ++j) {
        int i = base + t + 256 * j;
        if (i < n) s += deg[i];
    }
    #pragma unroll
    for (int off = 1; off < 64; off <<= 1) s += __shfl_xor(s, off, 64);
    if ((t & 63) == 0) wsum[t >> 6] = s;
    __syncthreads();
    if (t == 0) partial[blockIdx.x] = wsum[0] + wsum[1] + wsum[2] + wsum[3];
}

// exclusive scan finalize (computes own block base from partial[]) +
// alone-node detection (deg==0). Requires nparts <= 64.
__global__ __launch_bounds__(256) void scan_final_kernel(const int* __restrict__ deg,
                                                         const int* __restrict__ partial,
                                                         int* __restrict__ row_off,
                                                         int* __restrict__ alone_list,
                                                         int* __restrict__ alone_count, int n) {
    __shared__ int wsum[4];
    __shared__ int sbase;
    int bid = blockIdx.x;
    int t = threadIdx.x, lane = t & 63, wid = t >> 6;
    if (wid == 0) {
        int v = (lane < bid) ? partial[lane] : 0;
        #pragma unroll
        for (int off = 1; off < 64; off <<= 1) v += __shfl_xor(v, off, 64);
        if (lane == 0) sbase = v;
    }
    int base = bid * 1024;
    int i0 = base + t * 4;
    int v0 = (i0 + 0 < n) ? deg[i0 + 0] : 0;
    int v1 = (i0 + 1 < n) ? deg[i0 + 1] : 0;
    int v2 = (i0 + 2 < n) ? deg[i0 + 2] : 0;
    int v3 = (i0 + 3 < n) ? deg[i0 + 3] : 0;
    int s = v0 + v1 + v2 + v3;
    int x = s;
    #pragma unroll
    for (int off = 1; off < 64; off <<= 1) {
        int y = __shfl_up(x, off, 64);
        if (lane >= off) x += y;
    }
    if (lane == 63) wsum[wid] = x;
    __syncthreads();
    int wbase = 0;
    #pragma unroll
    for (int w = 0; w < 4; ++w) { int ws = wsum[w]; if (w < wid) wbase += ws; }
    int p = sbase + wbase + x - s;
    if (i0 + 0 <= n) row_off[i0 + 0] = p;
    p += v0;
    if (i0 + 1 <= n) row_off[i0 + 1] = p;
    p += v1;
    if (i0 + 2 <= n) row_off[i0 + 2] = p;
    p += v2;
    if (i0 + 3 <= n) row_off[i0 + 3] = p;
    if (i0 + 0 < n && v0 == 0) { int q = atomicAdd(alone_count, 1); if (q < ALONE_CAP) alone_list[q] = i0; }
    if (i0 + 1 < n && v1 == 0) { int q = atomicAdd(alone_count, 1); if (q < ALONE_CAP) alone_list[q] = i0 + 1; }
    if (i0 + 2 < n && v2 == 0) { int q = atomicAdd(alone_count, 1); if (q < ALONE_CAP) alone_list[q] = i0 + 2; }
    if (i0 + 3 < n && v3 == 0) { int q = atomicAdd(alone_count, 1); if (q < ALONE_CAP) alone_list[q] = i0 + 3; }
}

// edges packed as uint: src | (ety << 16). Valid: N_ENTS=50000<2^16, N_RELS=200.
__global__ __launch_bounds__(256) void scatter_kernel(
    const int* __restrict__ src, const int* __restrict__ dst,
    const int* __restrict__ ety, const int* __restrict__ row_off,
    int* __restrict__ cursor, unsigned* __restrict__ edges, int e) {
    int i = blockIdx.x * 256 + threadIdx.x;
    if (i < e) {
        int v = dst[i];
        int pos = row_off[v] + atomicAdd(&cursor[v], 1);
        edges[pos] = (unsigned)src[i] | ((unsigned)ety[i] << 16);
    }
}

// --------------------------------------------------- fused per-layer kernel
// v7 (R6 post-mortem: serial 16-node gather per wave starved TLP).
// CHAIN-PARALLEL gather: lane (quad,l16) owns the 32 output columns
// [kc*32+quad*8 .. +7] of node row_base+l16 and accumulates them in 8 named
// float4 regs -- exactly the MFMA A-fragment layout. Each wave thus runs 16
// INDEPENDENT edge chains (one per l16 group); 2 blocks/CU x 4 waves x 16 =
// 128 chains/CU (2x the old separate-agg's 64). No cross-lane reduce, no S
// in LDS (32KB ldsB only), S feeds GEMM A directly from registers.
// Edge word prefetched 1-deep. GEMM phase = proven R5 macro structure.
// Alias-safety: layer0 gathers from ent (never Esp), H-hoist reads own Esp
// rows, writes own Esp rows -> safe. Layer1 never writes Esp.
template <int SPLIT>
__global__ __launch_bounds__(256, 2) void fused_layer_kernel(
    const float* __restrict__ gf, const unsigned* __restrict__ gs,
    const unsigned* __restrict__ Hsp,
    const float* __restrict__ rel, const float* __restrict__ norm,
    const int* __restrict__ row_off, const unsigned* __restrict__ edges,
    const ushort* __restrict__ Pnh, const ushort* __restrict__ Pnl,
    const ushort* __restrict__ Plh, const ushort* __restrict__ Pll,
    float* out, unsigned* Osp, int n) {
    __shared__ ushort ldsB[2][2][4096];     // 32 KB B double-buffer

    const int tid = threadIdx.x;
    const int wave = tid >> 6, lane = tid & 63;
    const int quad = lane >> 4, l16 = lane & 15;
    const int row_base = blockIdx.x * 64 + wave * 16;
    const int q8 = quad * 8;

    const int v = row_base + l16;
    const int vc = (v > n - 1) ? (n - 1) : v;
    const size_t arow = (size_t)vc * 128;

    // ---- stage B slice 0 (sits in LDS across the gather; barrier below)
    {
        uint4 t0 = *(const uint4*)(Pnh + tid * 8);
        uint4 t1 = *(const uint4*)(Pnh + 2048 + tid * 8);
        uint4 t2 = *(const uint4*)(Pnl + tid * 8);
        uint4 t3 = *(const uint4*)(Pnl + 2048 + tid * 8);
        *(uint4*)&ldsB[0][0][tid * 8] = t0;
        *(uint4*)&ldsB[0][0][2048 + tid * 8] = t1;
        *(uint4*)&ldsB[0][1][tid * 8] = t2;
        *(uint4*)&ldsB[0][1][2048 + tid * 8] = t3;
    }

    // ---- gather: lane accumulates its own 32 columns of node v
    float4 Sa[8];
    #pragma unroll
    for (int i = 0; i < 8; ++i) Sa[i] = make_float4(0.f, 0.f, 0.f, 0.f);

    int es = 0, ee = 0;
    if (v < n) { es = row_off[v]; ee = row_off[v + 1]; }
    unsigned q = (es < ee) ? edges[es] : 0u;
    for (int e = es; e < ee; ++e) {
        unsigned qn = (e + 1 < ee) ? edges[e + 1] : 0u;  // prefetch next word
        const size_t hb = (size_t)(q & 0xFFFFu) * 128 + q8;
        const size_t rb = (size_t)(q >> 16) * 128 + q8;
        #pragma unroll
        for (int kc = 0; kc < 4; ++kc) {
            float4 h0, h1;
            if (SPLIT) {
                h0 = recon4(*(const uint4*)&gs[hb + kc * 32]);
                h1 = recon4(*(const uint4*)&gs[hb + kc * 32 + 4]);
            } else {
                h0 = *(const float4*)&gf[hb + kc * 32];
                h1 = *(const float4*)&gf[hb + kc * 32 + 4];
            }
            float4 r0 = *(const float4*)&rel[rb + kc * 32];
            float4 r1 = *(const float4*)&rel[rb + kc * 32 + 4];
            Sa[kc * 2].x     += h0.x + r0.x;
            Sa[kc * 2].y     += h0.y + r0.y;
            Sa[kc * 2].z     += h0.z + r0.z;
            Sa[kc * 2].w     += h0.w + r0.w;
            Sa[kc * 2 + 1].x += h1.x + r1.x;
            Sa[kc * 2 + 1].y += h1.y + r1.y;
            Sa[kc * 2 + 1].z += h1.z + r1.z;
            Sa[kc * 2 + 1].w += h1.w + r1.w;
        }
        q = qn;
    }
    {
        const float nm = (v < n) ? norm[v] : 0.f;
        #pragma unroll
        for (int i = 0; i < 8; ++i) {
            Sa[i].x *= nm; Sa[i].y *= nm; Sa[i].z *= nm; Sa[i].w *= nm;
        }
    }

    // ---- hoist own-row H slab (issues before barrier; consumed step 4+)
    uint4 h00 = *(const uint4*)(Hsp + arow + 0 * 32 + q8);
    uint4 h01 = *(const uint4*)(Hsp + arow + 0 * 32 + q8 + 4);
    uint4 h10 = *(const uint4*)(Hsp + arow + 1 * 32 + q8);
    uint4 h11 = *(const uint4*)(Hsp + arow + 1 * 32 + q8 + 4);
    uint4 h20 = *(const uint4*)(Hsp + arow + 2 * 32 + q8);
    uint4 h21 = *(const uint4*)(Hsp + arow + 2 * 32 + q8 + 4);
    uint4 h30 = *(const uint4*)(Hsp + arow + 3 * 32 + q8);
    uint4 h31 = *(const uint4*)(Hsp + arow + 3 * 32 + q8 + 4);

    __syncthreads();  // B slice 0 visible

    ffrag acc[8];
    #pragma unroll
    for (int ct = 0; ct < 8; ++ct) acc[ct] = (ffrag)0.f;

#define GSTAGE(NPH, NPL, NKC)                                                    \
        s0_ = *(const uint4*)((NPH) + (NKC) * 4096 + tid * 8);                   \
        s1_ = *(const uint4*)((NPH) + (NKC) * 4096 + 2048 + tid * 8);            \
        s2_ = *(const uint4*)((NPL) + (NKC) * 4096 + tid * 8);                   \
        s3_ = *(const uint4*)((NPL) + (NKC) * 4096 + 2048 + tid * 8);

#define GCOMPUTE(IT)                                                             \
        bfrag bh[8], bl[8];                                                      \
        _Pragma("unroll")                                                        \
        for (int ct = 0; ct < 8; ++ct) {                                         \
            bh[ct] = *(const bfrag*)&ldsB[(IT) & 1][0][ct * 512 + lane * 8];     \
            bl[ct] = *(const bfrag*)&ldsB[(IT) & 1][1][ct * 512 + lane * 8];     \
        }                                                                        \
        _Pragma("unroll")                                                        \
        for (int ct = 0; ct < 8; ++ct)                                           \
            acc[ct] = __builtin_amdgcn_mfma_f32_16x16x32_bf16(ah, bh[ct], acc[ct], 0, 0, 0); \
        _Pragma("unroll")                                                        \
        for (int ct = 0; ct < 8; ++ct)                                           \
            acc[ct] = __builtin_amdgcn_mfma_f32_16x16x32_bf16(ah, bl[ct], acc[ct], 0, 0, 0); \
        _Pragma("unroll")                                                        \
        for (int ct = 0; ct < 8; ++ct)                                           \
            acc[ct] = __builtin_amdgcn_mfma_f32_16x16x32_bf16(al, bh[ct], acc[ct], 0, 0, 0);

#define GFINISH(IT, HAVE)                                                        \
        if (HAVE) {                                                              \
            *(uint4*)&ldsB[((IT) + 1) & 1][0][tid * 8] = s0_;                    \
            *(uint4*)&ldsB[((IT) + 1) & 1][0][2048 + tid * 8] = s1_;             \
            *(uint4*)&ldsB[((IT) + 1) & 1][1][tid * 8] = s2_;                    \
            *(uint4*)&ldsB[((IT) + 1) & 1][1][2048 + tid * 8] = s3_;             \
            __syncthreads();                                                     \
        }

    // Steps 0-3: A from register-resident fp32 S (split in regs)
#define GSTEP_S(IT, KC, NPH, NPL, NKC, HAVE)                                     \
    {                                                                            \
        uint4 s0_, s1_, s2_, s3_;                                                \
        if (HAVE) { GSTAGE(NPH, NPL, NKC) }                                      \
        float4 f0 = Sa[(KC) * 2];                                                \
        float4 f1 = Sa[(KC) * 2 + 1];                                            \
        bfrag ah, al;                                                            \
        _Pragma("unroll")                                                        \
        for (int j = 0; j < 4; ++j) {                                            \
            float fa = ((const float*)&f0)[j];                                   \
            float fb = ((const float*)&f1)[j];                                   \
            unsigned short ha = rne16(fa);                                       \
            unsigned short hb = rne16(fb);                                       \
            ah[j]     = (short)ha; al[j]     = (short)rne16(fa - bf2f(ha));      \
            ah[j + 4] = (short)hb; al[j + 4] = (short)rne16(fb - bf2f(hb));      \
        }                                                                        \
        GCOMPUTE(IT)                                                             \
        GFINISH(IT, HAVE)                                                        \
    }

    // Steps 4-7: A from hoisted H registers (interleaved split)
#define GSTEP_H(IT, A0, A1, NPH, NPL, NKC, HAVE)                                 \
    {                                                                            \
        uint4 s0_, s1_, s2_, s3_;                                                \
        if (HAVE) { GSTAGE(NPH, NPL, NKC) }                                      \
        bfrag ah, al;                                                            \
        _Pragma("unroll")                                                        \
        for (int j = 0; j < 4; ++j) {                                            \
            unsigned u0 = ((const unsigned*)&(A0))[j];                           \
            unsigned u1 = ((const unsigned*)&(A1))[j];                           \
            ah[j]     = (short)(u0 >> 16); al[j]     = (short)(u0 & 0xFFFFu);    \
            ah[j + 4] = (short)(u1 >> 16); al[j + 4] = (short)(u1 & 0xFFFFu);    \
        }                                                                        \
        GCOMPUTE(IT)                                                             \
        GFINISH(IT, HAVE)                                                        \
    }

    GSTEP_S(0, 0, Pnh, Pnl, 1, 1)
    GSTEP_S(1, 1, Pnh, Pnl, 2, 1)
    GSTEP_S(2, 2, Pnh, Pnl, 3, 1)
    GSTEP_S(3, 3, Plh, Pll, 0, 1)
    GSTEP_H(4, h00, h01, Plh, Pll, 1, 1)
    GSTEP_H(5, h10, h11, Plh, Pll, 2, 1)
    GSTEP_H(6, h20, h21, Plh, Pll, 3, 1)
    GSTEP_H(7, h30, h31, Plh, Pll, 0, 0)
#undef GSTEP_S
#undef GSTEP_H
#undef GSTAGE
#undef GCOMPUTE
#undef GFINISH

    #pragma unroll
    for (int ct = 0; ct < 8; ++ct) {
        #pragma unroll
        for (int rg = 0; rg < 4; ++rg) {
            int r = row_base + quad * 4 + rg;
            if (r < n) {
                int c = ct * 16 + l16;
                float val = acc[ct][rg];
                val = val >= 0.f ? val : val * SLOPE;
                if (out) out[(size_t)r * 128 + c] = val;
                if (Osp) Osp[(size_t)r * 128 + c] = packsplit(val);
            }
        }
    }
}

// Alone nodes: o = leaky(hrow @ Wa).
// Layer 0 (by_node=1): hrow = ent[v]; writes Osp (h1 split) + asave fp32.
// Layer 1 (by_node=0): hrow = asave[i]; writes out fp32.
__global__ __launch_bounds__(128) void fixup_kernel(
    const float* __restrict__ Hrows, int by_node,
    const float* __restrict__ Wa,
    const int* __restrict__ alone_list, const int* __restrict__ alone_count,
    float* out, unsigned* Osp, float* asave) {
    int cnt = *alone_count;
    if (cnt > ALONE_CAP) cnt = ALONE_CAP;
    int t = threadIdx.x;
    for (int i = blockIdx.x; i < cnt; i += gridDim.x) {
        int v = alone_list[i];
        const float* hrow = Hrows + (size_t)(by_node ? v : i) * 128;
        float acc = 0.f;
        for (int k = 0; k < 128; ++k)
            acc += hrow[k] * Wa[k * 128 + t];
        float o = acc >= 0.f ? acc : acc * SLOPE;
        if (out) out[(size_t)v * 128 + t] = o;
        if (Osp) Osp[(size_t)v * 128 + t] = packsplit(o);
        if (asave) asave[(size_t)i * 128 + t] = o;
    }
}

extern "C" void kernel_launch(void* const* d_in, const int* in_sizes, int n_in,
                              void* d_out, int out_size, void* d_ws, size_t ws_size,
                              hipStream_t stream) {
    const float* ent  = (const float*)d_in[0];
    const float* rel  = (const float*)d_in[1];
    const float* norm = (const float*)d_in[2];
    const float* Wn   = (const float*)d_in[3];
    const float* Wl   = (const float*)d_in[4];
    const float* Wa   = (const float*)d_in[5];
    const int*   src  = (const int*)d_in[6];
    const int*   dst  = (const int*)d_in[7];
    const int*   ety  = (const int*)d_in[8];
    float* out = (float*)d_out;

    const int n = in_sizes[2];   // 50000
    const int e = in_sizes[7];   // 500000

    // workspace layout
    char* ws = (char*)d_ws;
    int* deg         = (int*)ws;          // n
    int* cursor      = deg + n;           // n
    int* alone_count = cursor + n;        // 1
    size_t zbytes = (size_t)(2 * n + 1) * sizeof(int);
    size_t p = (zbytes + 255) & ~(size_t)255;
    int* row_off = (int*)(ws + p);        // n+1
    p += (((size_t)(n + 1) * 4) + 255) & ~(size_t)255;
    int* partial = (int*)(ws + p);        // <=64
    p += 256;
    int* alone_list = (int*)(ws + p);     // ALONE_CAP
    p += (((size_t)ALONE_CAP * 4) + 255) & ~(size_t)255;
    float* asave = (float*)(ws + p);      // ALONE_CAP*128 f32 (1 MB)
    p += (((size_t)ALONE_CAP * 128 * 4) + 255) & ~(size_t)255;
    unsigned* edges = (unsigned*)(ws + p);// e packed (2 MB)
    p += (((size_t)e * 4) + 255) & ~(size_t)255;
    unsigned* Esp = (unsigned*)(ws + p);  // ent split; becomes h1 split (25.6 MB)
    p += (((size_t)n * 128 * 4) + 255) & ~(size_t)255;
    ushort* packW = (ushort*)(ws + p);    // 4 mats x (hi16K + lo16K) (256 KB)
    p += 4 * 32768 * 2;

    const int eb = (e + 255) / 256;             // 1954
    const int cb = (n * 32 + 255) / 256;        // 6250 (float4 units)
    const int nparts = (n + 1023) / 1024;       // 49 (<=64 required)
    const int gb = (n + 63) / 64;               // 782

    hipMemsetAsync(ws, 0, zbytes, stream);
    prep_kernel<<<eb + cb + 32, 256, 0, stream>>>(dst, deg, e, eb,
                                                  ent, Esp, n * 32, cb,
                                                  Wn, Wl, packW);
    scan_partial_kernel<<<nparts, 256, 0, stream>>>(deg, partial, n);
    scan_final_kernel<<<nparts, 256, 0, stream>>>(deg, partial, row_off,
                                                  alone_list, alone_count, n);
    scatter_kernel<<<eb, 256, 0, stream>>>(src, dst, ety, row_off, cursor, edges, e);

    // layer 0: gather from ent (fp32), H = Esp (ent split); writes Esp (h1 split)
    fused_layer_kernel<0><<<gb, 256, 0, stream>>>(
        ent, nullptr, Esp, rel, norm, row_off, edges,
        packW, packW + 16384, packW + 32768, packW + 49152,
        nullptr, Esp, n);
    fixup_kernel<<<16, 128, 0, stream>>>(ent, 1, Wa, alone_list, alone_count,
                                         nullptr, Esp, asave);

    // layer 1: gather from Esp (h1 split), H = Esp; writes out fp32
    fused_layer_kernel<1><<<gb, 256, 0, stream>>>(
        nullptr, Esp, Esp, rel, norm, row_off, edges,
        packW + 65536, packW + 81920, packW + 98304, packW + 114688,
        out, nullptr, n);
    fixup_kernel<<<16, 128, 0, stream>>>(asave, 0, Wa + 16384, alone_list, alone_count,
                                         out, nullptr, nullptr);
}

// Round 8
// 276.317 us; speedup vs baseline: 1.2919x; 1.2842x over previous
//
#include <hip/hip_runtime.h>

#define SLOPE 0.22916666666666666f  // (1/8 + 1/3) / 2
#define ALONE_CAP 2048              // expected alone nodes ~2.3

typedef __attribute__((ext_vector_type(8))) short bfrag;   // 8 x bf16 bits
typedef __attribute__((ext_vector_type(4))) float ffrag;   // 4 x f32 acc

__device__ __forceinline__ unsigned short rne16(float f) {
    unsigned u = __float_as_uint(f);
    return (unsigned short)((u + 0x7FFFu + ((u >> 16) & 1u)) >> 16);
}
__device__ __forceinline__ float bf2f(unsigned short h) {
    return __uint_as_float(((unsigned)h) << 16);
}
// interleaved split word: hi bf16 in [31:16], lo bf16 in [15:0]
__device__ __forceinline__ unsigned packsplit(float f) {
    unsigned short hi = rne16(f);
    unsigned short lo = rne16(f - bf2f(hi));
    return ((unsigned)hi << 16) | lo;
}
__device__ __forceinline__ float recon(unsigned u) {
    return __uint_as_float(u & 0xFFFF0000u) + __uint_as_float(u << 16);
}
__device__ __forceinline__ float4 recon4(uint4 u) {
    return make_float4(recon(u.x), recon(u.y), recon(u.z), recon(u.w));
}

// ---------------------------------------------------------------- prep
// Fused: [0,eb) count in-degrees; [eb,eb+cb) split ent -> interleaved Esp;
// [eb+cb, +32) pack W into MFMA B-fragment order (hi/lo planes).
// B layout (fragment-major, per plane of 16384 shorts):
//   plane[kc*4096 + ct*512 + (quad*16 + l16)*8 + j] = bf16(W[kc*32+quad*8+j][ct*16+l16])
// so a wave's ds_read_b128 for column-tile ct is contiguous 1KB (lane*16B).
__global__ __launch_bounds__(256) void prep_kernel(
    const int* __restrict__ dst, int* __restrict__ deg, int e, int eb,
    const float* __restrict__ ent, unsigned* __restrict__ Esp,
    int total4, int cb,
    const float* __restrict__ Wn, const float* __restrict__ Wl,
    ushort* __restrict__ packW) {
    int b = blockIdx.x;
    if (b < eb) {
        int i = b * 256 + threadIdx.x;
        if (i < e) atomicAdd(&deg[dst[i]], 1);
    } else if (b < eb + cb) {
        int i = (b - eb) * 256 + threadIdx.x;
        if (i >= total4) return;
        float4 v = ((const float4*)ent)[i];
        uint4 w;
        w.x = packsplit(v.x); w.y = packsplit(v.y);
        w.z = packsplit(v.z); w.w = packsplit(v.w);
        ((uint4*)Esp)[i] = w;
    } else {
        int t = (b - eb - cb) * 256 + threadIdx.x;
        if (t >= 4 * 4 * 128 * 4) return;
        int quad = t & 3;
        int nn   = (t >> 2) & 127;
        int kc   = (t >> 9) & 3;
        int mat  = t >> 11;   // 0=Wn L0, 1=Wl L0, 2=Wn L1, 3=Wl L1
        const float* W = ((mat & 1) ? Wl : Wn) + (mat >> 1) * 16384;
        ushort* oh = packW + mat * 32768;
        ushort* ol = oh + 16384;
        int obase = kc * 4096 + (nn >> 4) * 512 + (quad * 16 + (nn & 15)) * 8;
        #pragma unroll
        for (int j = 0; j < 8; ++j) {
            float w = W[(kc * 32 + quad * 8 + j) * 128 + nn];
            unsigned short hi = rne16(w);
            oh[obase + j] = hi;
            ol[obase + j] = rne16(w - bf2f(hi));
        }
    }
}

// --- scan: partial block sums, then finalize (aux prefix inlined) ---------
__global__ __launch_bounds__(256) void scan_partial_kernel(const int* __restrict__ deg,
                                                           int* __restrict__ partial, int n) {
    __shared__ int wsum[4];
    int base = blockIdx.x * 1024;
    int t = threadIdx.x;
    int s = 0;
    #pragma unroll
    for (int j = 0; j < 4; ++j) {
        int i = base + t + 256 * j;
        if (i < n) s += deg[i];
    }
    #pragma unroll
    for (int off = 1; off < 64; off <<= 1) s += __shfl_xor(s, off, 64);
    if ((t & 63) == 0) wsum[t >> 6] = s;
    __syncthreads();
    if (t == 0) partial[blockIdx.x] = wsum[0] + wsum[1] + wsum[2] + wsum[3];
}

// exclusive scan finalize (computes own block base from partial[]) +
// alone-node detection (deg==0). Requires nparts <= 64.
__global__ __launch_bounds__(256) void scan_final_kernel(const int* __restrict__ deg,
                                                         const int* __restrict__ partial,
                                                         int* __restrict__ row_off,
                                                         int* __restrict__ alone_list,
                                                         int* __restrict__ alone_count, int n) {
    __shared__ int wsum[4];
    __shared__ int sbase;
    int bid = blockIdx.x;
    int t = threadIdx.x, lane = t & 63, wid = t >> 6;
    if (wid == 0) {
        int v = (lane < bid) ? partial[lane] : 0;
        #pragma unroll
        for (int off = 1; off < 64; off <<= 1) v += __shfl_xor(v, off, 64);
        if (lane == 0) sbase = v;
    }
    int base = bid * 1024;
    int i0 = base + t * 4;
    int v0 = (i0 + 0 < n) ? deg[i0 + 0] : 0;
    int v1 = (i0 + 1 < n) ? deg[i0 + 1] : 0;
    int v2 = (i0 + 2 < n) ? deg[i0 + 2] : 0;
    int v3 = (i0 + 3 < n) ? deg[i0 + 3] : 0;
    int s = v0 + v1 + v2 + v3;
    int x = s;
    #pragma unroll
    for (int off = 1; off < 64; off <<= 1) {
        int y = __shfl_up(x, off, 64);
        if (lane >= off) x += y;
    }
    if (lane == 63) wsum[wid] = x;
    __syncthreads();
    int wbase = 0;
    #pragma unroll
    for (int w = 0; w < 4; ++w) { int ws = wsum[w]; if (w < wid) wbase += ws; }
    int p = sbase + wbase + x - s;
    if (i0 + 0 <= n) row_off[i0 + 0] = p;
    p += v0;
    if (i0 + 1 <= n) row_off[i0 + 1] = p;
    p += v1;
    if (i0 + 2 <= n) row_off[i0 + 2] = p;
    p += v2;
    if (i0 + 3 <= n) row_off[i0 + 3] = p;
    if (i0 + 0 < n && v0 == 0) { int q = atomicAdd(alone_count, 1); if (q < ALONE_CAP) alone_list[q] = i0; }
    if (i0 + 1 < n && v1 == 0) { int q = atomicAdd(alone_count, 1); if (q < ALONE_CAP) alone_list[q] = i0 + 1; }
    if (i0 + 2 < n && v2 == 0) { int q = atomicAdd(alone_count, 1); if (q < ALONE_CAP) alone_list[q] = i0 + 2; }
    if (i0 + 3 < n && v3 == 0) { int q = atomicAdd(alone_count, 1); if (q < ALONE_CAP) alone_list[q] = i0 + 3; }
}

// edges packed as uint: src | (ety << 16). Valid: N_ENTS=50000<2^16, N_RELS=200.
__global__ __launch_bounds__(256) void scatter_kernel(
    const int* __restrict__ src, const int* __restrict__ dst,
    const int* __restrict__ ety, const int* __restrict__ row_off,
    int* __restrict__ cursor, unsigned* __restrict__ edges, int e) {
    int i = blockIdx.x * 256 + threadIdx.x;
    if (i < e) {
        int v = dst[i];
        int pos = row_off[v] + atomicAdd(&cursor[v], 1);
        edges[pos] = (unsigned)src[i] | ((unsigned)ety[i] << 16);
    }
}

// ------------------------------------------------------- per-layer kernels
// S[v] = norm[v] * sum_e (h[src]+rel[et]); emitted interleaved hi/lo (Ssp).
// SPLIT=0: h is fp32 (hf). SPLIT=1: h is interleaved split (hs), reconstruct.
// One wave/node; half-wave/edge; 8 edges in flight per wave. 50K waves ->
// max TLP; L3-BW-bound (~512MB/layer through L3) -- near its ceiling.
template <int SPLIT>
__global__ __launch_bounds__(256) void agg_kernel(
    const float* __restrict__ hf, const unsigned* __restrict__ hs,
    const float* __restrict__ rel,
    const float* __restrict__ norm, const int* __restrict__ row_off,
    const unsigned* __restrict__ edges, unsigned* __restrict__ Ssp, int n) {
    int wave = threadIdx.x >> 6, lane = threadIdx.x & 63;
    int v = blockIdx.x * 4 + wave;
    if (v >= n) return;
    int s0 = row_off[v], s1 = row_off[v + 1];
    float nm = norm[v];
    int half = lane >> 5;
    int c4 = (lane & 31) * 4;
    float4 acc = make_float4(0.f, 0.f, 0.f, 0.f);
    int e = s0;
    for (; e + 7 < s1; e += 8) {
        unsigned q0 = edges[e + half];
        unsigned q1 = edges[e + 2 + half];
        unsigned q2 = edges[e + 4 + half];
        unsigned q3 = edges[e + 6 + half];
        float4 h0, h1, h2, h3;
        if (SPLIT) {
            h0 = recon4(*(const uint4*)&hs[(size_t)(q0 & 0xFFFFu) * 128 + c4]);
            h1 = recon4(*(const uint4*)&hs[(size_t)(q1 & 0xFFFFu) * 128 + c4]);
            h2 = recon4(*(const uint4*)&hs[(size_t)(q2 & 0xFFFFu) * 128 + c4]);
            h3 = recon4(*(const uint4*)&hs[(size_t)(q3 & 0xFFFFu) * 128 + c4]);
        } else {
            h0 = *(const float4*)&hf[(size_t)(q0 & 0xFFFFu) * 128 + c4];
            h1 = *(const float4*)&hf[(size_t)(q1 & 0xFFFFu) * 128 + c4];
            h2 = *(const float4*)&hf[(size_t)(q2 & 0xFFFFu) * 128 + c4];
            h3 = *(const float4*)&hf[(size_t)(q3 & 0xFFFFu) * 128 + c4];
        }
        float4 r0 = *(const float4*)&rel[(size_t)(q0 >> 16) * 128 + c4];
        float4 r1 = *(const float4*)&rel[(size_t)(q1 >> 16) * 128 + c4];
        float4 r2 = *(const float4*)&rel[(size_t)(q2 >> 16) * 128 + c4];
        float4 r3 = *(const float4*)&rel[(size_t)(q3 >> 16) * 128 + c4];
        acc.x += ((h0.x + r0.x) + (h1.x + r1.x)) + ((h2.x + r2.x) + (h3.x + r3.x));
        acc.y += ((h0.y + r0.y) + (h1.y + r1.y)) + ((h2.y + r2.y) + (h3.y + r3.y));
        acc.z += ((h0.z + r0.z) + (h1.z + r1.z)) + ((h2.z + r2.z) + (h3.z + r3.z));
        acc.w += ((h0.w + r0.w) + (h1.w + r1.w)) + ((h2.w + r2.w) + (h3.w + r3.w));
    }
    for (; e + 1 < s1; e += 2) {
        unsigned q0 = edges[e + half];
        float4 h0 = SPLIT ? recon4(*(const uint4*)&hs[(size_t)(q0 & 0xFFFFu) * 128 + c4])
                          : *(const float4*)&hf[(size_t)(q0 & 0xFFFFu) * 128 + c4];
        float4 r0 = *(const float4*)&rel[(size_t)(q0 >> 16) * 128 + c4];
        acc.x += h0.x + r0.x; acc.y += h0.y + r0.y;
        acc.z += h0.z + r0.z; acc.w += h0.w + r0.w;
    }
    if (e < s1 && half == 0) {
        unsigned q0 = edges[e];
        float4 h0 = SPLIT ? recon4(*(const uint4*)&hs[(size_t)(q0 & 0xFFFFu) * 128 + c4])
                          : *(const float4*)&hf[(size_t)(q0 & 0xFFFFu) * 128 + c4];
        float4 r0 = *(const float4*)&rel[(size_t)(q0 >> 16) * 128 + c4];
        acc.x += h0.x + r0.x; acc.y += h0.y + r0.y;
        acc.z += h0.z + r0.z; acc.w += h0.w + r0.w;
    }
    acc.x += __shfl_xor(acc.x, 32, 64);
    acc.y += __shfl_xor(acc.y, 32, 64);
    acc.z += __shfl_xor(acc.z, 32, 64);
    acc.w += __shfl_xor(acc.w, 32, 64);
    if (half == 0) {
        uint4 w;
        w.x = packsplit(acc.x * nm); w.y = packsplit(acc.y * nm);
        w.z = packsplit(acc.z * nm); w.w = packsplit(acc.w * nm);
        *(uint4*)&Ssp[(size_t)v * 128 + c4] = w;
    }
}

// out = leaky(S@Wn + H@Wl) via bf16-split MFMA (3 products).
// Block = 256 thr = 4 waves; wave tile 16 rows x 128 cols; grid ceil(n/64).
// v6 (R7 post-mortem: revert fusion; cut gemm's 8 latency exposures):
// 64KB LDS holds ONE FULL MATRIX (4 kc-slices x hi/lo). Stage Wn once ->
// steps 0-3 BARRIER-FREE (read-only LDS) -> barrier -> stage Wl + hoist H
// A-slab (latencies overlap, drained together) -> barrier -> steps 4-7
// barrier-free. Latency exposures 8->2, barriers 8->3. All loads named/
// static (R4 spill lesson). LDS 64KB -> 2 blocks/CU.
// Alias-safe: each wave reads/writes only its own 16 rows of A/out; H reads
// complete (consumed by MFMAs) before epilogue stores.
__global__ __launch_bounds__(256, 2) void gemm_mfma_kernel(
    const unsigned* __restrict__ Ssp, const unsigned* Hsp,
    const ushort* __restrict__ Pnh, const ushort* __restrict__ Pnl,
    const ushort* __restrict__ Plh, const ushort* __restrict__ Pll,
    float* __restrict__ out, unsigned* Osp, int n) {
    __shared__ ushort ldsB[4][2][4096];  // [kc][plane hi/lo][8KB] = 64KB

    const int tid = threadIdx.x;
    const int wave = tid >> 6, lane = tid & 63;
    const int quad = lane >> 4, l16 = lane & 15;
    const int row_base = blockIdx.x * 64 + wave * 16;

    int r0c = row_base + l16;
    if (r0c > n - 1) r0c = n - 1;
    const size_t arow = (size_t)r0c * 128;
    const int q8 = quad * 8;

    ffrag acc[8];
    #pragma unroll
    for (int ct = 0; ct < 8; ++ct) acc[ct] = (ffrag)0.f;

    // Stage one full matrix (4 kc-slices, hi+lo) into the 64KB buffer.
    // 16 named loads then 16 ds_writes (16-wide MLP, no spill-prone arrays).
#define STAGE_MAT(PH, PL)                                                        \
    {                                                                            \
        uint4 t00 = *(const uint4*)((PH) + 0 * 4096 + tid * 8);                  \
        uint4 t01 = *(const uint4*)((PH) + 0 * 4096 + 2048 + tid * 8);           \
        uint4 t02 = *(const uint4*)((PL) + 0 * 4096 + tid * 8);                  \
        uint4 t03 = *(const uint4*)((PL) + 0 * 4096 + 2048 + tid * 8);           \
        uint4 t10 = *(const uint4*)((PH) + 1 * 4096 + tid * 8);                  \
        uint4 t11 = *(const uint4*)((PH) + 1 * 4096 + 2048 + tid * 8);           \
        uint4 t12 = *(const uint4*)((PL) + 1 * 4096 + tid * 8);                  \
        uint4 t13 = *(const uint4*)((PL) + 1 * 4096 + 2048 + tid * 8);           \
        uint4 t20 = *(const uint4*)((PH) + 2 * 4096 + tid * 8);                  \
        uint4 t21 = *(const uint4*)((PH) + 2 * 4096 + 2048 + tid * 8);           \
        uint4 t22 = *(const uint4*)((PL) + 2 * 4096 + tid * 8);                  \
        uint4 t23 = *(const uint4*)((PL) + 2 * 4096 + 2048 + tid * 8);           \
        uint4 t30 = *(const uint4*)((PH) + 3 * 4096 + tid * 8);                  \
        uint4 t31 = *(const uint4*)((PH) + 3 * 4096 + 2048 + tid * 8);           \
        uint4 t32 = *(const uint4*)((PL) + 3 * 4096 + tid * 8);                  \
        uint4 t33 = *(const uint4*)((PL) + 3 * 4096 + 2048 + tid * 8);           \
        *(uint4*)&ldsB[0][0][tid * 8] = t00;                                     \
        *(uint4*)&ldsB[0][0][2048 + tid * 8] = t01;                              \
        *(uint4*)&ldsB[0][1][tid * 8] = t02;                                     \
        *(uint4*)&ldsB[0][1][2048 + tid * 8] = t03;                              \
        *(uint4*)&ldsB[1][0][tid * 8] = t10;                                     \
        *(uint4*)&ldsB[1][0][2048 + tid * 8] = t11;                              \
        *(uint4*)&ldsB[1][1][tid * 8] = t12;                                     \
        *(uint4*)&ldsB[1][1][2048 + tid * 8] = t13;                              \
        *(uint4*)&ldsB[2][0][tid * 8] = t20;                                     \
        *(uint4*)&ldsB[2][0][2048 + tid * 8] = t21;                              \
        *(uint4*)&ldsB[2][1][tid * 8] = t22;                                     \
        *(uint4*)&ldsB[2][1][2048 + tid * 8] = t23;                              \
        *(uint4*)&ldsB[3][0][tid * 8] = t30;                                     \
        *(uint4*)&ldsB[3][0][2048 + tid * 8] = t31;                              \
        *(uint4*)&ldsB[3][1][tid * 8] = t32;                                     \
        *(uint4*)&ldsB[3][1][2048 + tid * 8] = t33;                              \
    }

    // One K-step: pure ds_read + MFMA (no barriers, no staging).
#define GSTEP(KC, A0, A1)                                                        \
    {                                                                            \
        bfrag bh[8], bl[8];                                                      \
        _Pragma("unroll")                                                        \
        for (int ct = 0; ct < 8; ++ct) {                                         \
            bh[ct] = *(const bfrag*)&ldsB[KC][0][ct * 512 + lane * 8];           \
            bl[ct] = *(const bfrag*)&ldsB[KC][1][ct * 512 + lane * 8];           \
        }                                                                        \
        bfrag ah, al;                                                            \
        _Pragma("unroll")                                                        \
        for (int j = 0; j < 4; ++j) {                                            \
            unsigned u0 = ((const unsigned*)&(A0))[j];                           \
            unsigned u1 = ((const unsigned*)&(A1))[j];                           \
            ah[j]     = (short)(u0 >> 16); al[j]     = (short)(u0 & 0xFFFFu);    \
            ah[j + 4] = (short)(u1 >> 16); al[j + 4] = (short)(u1 & 0xFFFFu);    \
        }                                                                        \
        _Pragma("unroll")                                                        \
        for (int ct = 0; ct < 8; ++ct)                                           \
            acc[ct] = __builtin_amdgcn_mfma_f32_16x16x32_bf16(ah, bh[ct], acc[ct], 0, 0, 0); \
        _Pragma("unroll")                                                        \
        for (int ct = 0; ct < 8; ++ct)                                           \
            acc[ct] = __builtin_amdgcn_mfma_f32_16x16x32_bf16(ah, bl[ct], acc[ct], 0, 0, 0); \
        _Pragma("unroll")                                                        \
        for (int ct = 0; ct < 8; ++ct)                                           \
            acc[ct] = __builtin_amdgcn_mfma_f32_16x16x32_bf16(al, bh[ct], acc[ct], 0, 0, 0); \
    }

    // ---- prologue: S-half A hoist (8 named uint4) + stage Wn; one drain
    uint4 a00 = *(const uint4*)(Ssp + arow + 0 * 32 + q8);
    uint4 a01 = *(const uint4*)(Ssp + arow + 0 * 32 + q8 + 4);
    uint4 a10 = *(const uint4*)(Ssp + arow + 1 * 32 + q8);
    uint4 a11 = *(const uint4*)(Ssp + arow + 1 * 32 + q8 + 4);
    uint4 a20 = *(const uint4*)(Ssp + arow + 2 * 32 + q8);
    uint4 a21 = *(const uint4*)(Ssp + arow + 2 * 32 + q8 + 4);
    uint4 a30 = *(const uint4*)(Ssp + arow + 3 * 32 + q8);
    uint4 a31 = *(const uint4*)(Ssp + arow + 3 * 32 + q8 + 4);
    STAGE_MAT(Pnh, Pnl)
    __syncthreads();  // barrier 1: Wn staged (drains A hoist too)

    GSTEP(0, a00, a01)
    GSTEP(1, a10, a11)
    GSTEP(2, a20, a21)
    GSTEP(3, a30, a31)

    __syncthreads();  // barrier 2: all Wn reads complete

    // ---- midpoint: H-half A hoist + stage Wl; latencies overlap, one drain
    uint4 a40 = *(const uint4*)(Hsp + arow + 0 * 32 + q8);
    uint4 a41 = *(const uint4*)(Hsp + arow + 0 * 32 + q8 + 4);
    uint4 a50 = *(const uint4*)(Hsp + arow + 1 * 32 + q8);
    uint4 a51 = *(const uint4*)(Hsp + arow + 1 * 32 + q8 + 4);
    uint4 a60 = *(const uint4*)(Hsp + arow + 2 * 32 + q8);
    uint4 a61 = *(const uint4*)(Hsp + arow + 2 * 32 + q8 + 4);
    uint4 a70 = *(const uint4*)(Hsp + arow + 3 * 32 + q8);
    uint4 a71 = *(const uint4*)(Hsp + arow + 3 * 32 + q8 + 4);
    STAGE_MAT(Plh, Pll)
    __syncthreads();  // barrier 3: Wl staged (drains H hoist too)

    GSTEP(0, a40, a41)
    GSTEP(1, a50, a51)
    GSTEP(2, a60, a61)
    GSTEP(3, a70, a71)
#undef GSTEP
#undef STAGE_MAT

    #pragma unroll
    for (int ct = 0; ct < 8; ++ct) {
        #pragma unroll
        for (int rg = 0; rg < 4; ++rg) {
            int r = row_base + quad * 4 + rg;
            if (r < n) {
                int c = ct * 16 + l16;
                float v = acc[ct][rg];
                v = v >= 0.f ? v : v * SLOPE;
                if (out) out[(size_t)r * 128 + c] = v;
                if (Osp) Osp[(size_t)r * 128 + c] = packsplit(v);
            }
        }
    }
}

// Alone nodes: o = leaky(hrow @ Wa).
// Layer 0 (by_node=1): hrow = ent[v]; writes Osp (h1 split) + asave fp32.
// Layer 1 (by_node=0): hrow = asave[i]; writes out fp32.
__global__ __launch_bounds__(128) void fixup_kernel(
    const float* __restrict__ Hrows, int by_node,
    const float* __restrict__ Wa,
    const int* __restrict__ alone_list, const int* __restrict__ alone_count,
    float* out, unsigned* Osp, float* asave) {
    int cnt = *alone_count;
    if (cnt > ALONE_CAP) cnt = ALONE_CAP;
    int t = threadIdx.x;
    for (int i = blockIdx.x; i < cnt; i += gridDim.x) {
        int v = alone_list[i];
        const float* hrow = Hrows + (size_t)(by_node ? v : i) * 128;
        float acc = 0.f;
        for (int k = 0; k < 128; ++k)
            acc += hrow[k] * Wa[k * 128 + t];
        float o = acc >= 0.f ? acc : acc * SLOPE;
        if (out) out[(size_t)v * 128 + t] = o;
        if (Osp) Osp[(size_t)v * 128 + t] = packsplit(o);
        if (asave) asave[(size_t)i * 128 + t] = o;
    }
}

extern "C" void kernel_launch(void* const* d_in, const int* in_sizes, int n_in,
                              void* d_out, int out_size, void* d_ws, size_t ws_size,
                              hipStream_t stream) {
    const float* ent  = (const float*)d_in[0];
    const float* rel  = (const float*)d_in[1];
    const float* norm = (const float*)d_in[2];
    const float* Wn   = (const float*)d_in[3];
    const float* Wl   = (const float*)d_in[4];
    const float* Wa   = (const float*)d_in[5];
    const int*   src  = (const int*)d_in[6];
    const int*   dst  = (const int*)d_in[7];
    const int*   ety  = (const int*)d_in[8];
    float* out = (float*)d_out;

    const int n = in_sizes[2];   // 50000
    const int e = in_sizes[7];   // 500000

    // workspace layout
    char* ws = (char*)d_ws;
    int* deg         = (int*)ws;          // n
    int* cursor      = deg + n;           // n
    int* alone_count = cursor + n;        // 1
    size_t zbytes = (size_t)(2 * n + 1) * sizeof(int);
    size_t p = (zbytes + 255) & ~(size_t)255;
    int* row_off = (int*)(ws + p);        // n+1
    p += (((size_t)(n + 1) * 4) + 255) & ~(size_t)255;
    int* partial = (int*)(ws + p);        // <=64
    p += 256;
    int* alone_list = (int*)(ws + p);     // ALONE_CAP
    p += (((size_t)ALONE_CAP * 4) + 255) & ~(size_t)255;
    float* asave = (float*)(ws + p);      // ALONE_CAP*128 f32 (1 MB)
    p += (((size_t)ALONE_CAP * 128 * 4) + 255) & ~(size_t)255;
    unsigned* edges = (unsigned*)(ws + p);// e packed (2 MB)
    p += (((size_t)e * 4) + 255) & ~(size_t)255;
    unsigned* Ssp = (unsigned*)(ws + p);  // n*128 interleaved split (25.6 MB)
    p += (((size_t)n * 128 * 4) + 255) & ~(size_t)255;
    unsigned* Esp = (unsigned*)(ws + p);  // ent split; becomes h1 split (25.6 MB)
    p += (((size_t)n * 128 * 4) + 255) & ~(size_t)255;
    ushort* packW = (ushort*)(ws + p);    // 4 mats x (hi16K + lo16K) (256 KB)
    p += 4 * 32768 * 2;

    const int eb = (e + 255) / 256;             // 1954
    const int cb = (n * 32 + 255) / 256;        // 6250 (float4 units)
    const int nparts = (n + 1023) / 1024;       // 49 (<=64 required)
    const int gb = (n + 63) / 64;               // 782
    const int ab = (n + 3) / 4;                 // 12500

    hipMemsetAsync(ws, 0, zbytes, stream);
    prep_kernel<<<eb + cb + 32, 256, 0, stream>>>(dst, deg, e, eb,
                                                  ent, Esp, n * 32, cb,
                                                  Wn, Wl, packW);
    scan_partial_kernel<<<nparts, 256, 0, stream>>>(deg, partial, n);
    scan_final_kernel<<<nparts, 256, 0, stream>>>(deg, partial, row_off,
                                                  alone_list, alone_count, n);
    scatter_kernel<<<eb, 256, 0, stream>>>(src, dst, ety, row_off, cursor, edges, e);

    // layer 0: ent -> h1 split (in Esp; alias-safe: waves write only rows they read)
    agg_kernel<0><<<ab, 256, 0, stream>>>(ent, nullptr, rel, norm, row_off, edges, Ssp, n);
    gemm_mfma_kernel<<<gb, 256, 0, stream>>>(Ssp, Esp,
                                             packW, packW + 16384,
                                             packW + 32768, packW + 49152,
                                             nullptr, Esp, n);
    fixup_kernel<<<16, 128, 0, stream>>>(ent, 1, Wa, alone_list, alone_count,
                                         nullptr, Esp, asave);

    // layer 1: h1 split -> out (fp32, d_out). fixup-2 reads asave.
    agg_kernel<1><<<ab, 256, 0, stream>>>(nullptr, Esp, rel, norm, row_off, edges, Ssp, n);
    gemm_mfma_kernel<<<gb, 256, 0, stream>>>(Ssp, Esp,
                                             packW + 65536, packW + 81920,
                                             packW + 98304, packW + 114688,
                                             out, nullptr, n);
    fixup_kernel<<<16, 128, 0, stream>>>(asave, 0, Wa + 16384, alone_list, alone_count,
                                         out, nullptr, nullptr);
}

// Round 10
// 275.501 us; speedup vs baseline: 1.2957x; 1.0030x over previous
//
#include <hip/hip_runtime.h>

#define SLOPE 0.22916666666666666f  // (1/8 + 1/3) / 2
#define ALONE_CAP 2048              // expected alone nodes ~2.3

typedef __attribute__((ext_vector_type(8))) short bfrag;   // 8 x bf16 bits
typedef __attribute__((ext_vector_type(4))) float ffrag;   // 4 x f32 acc

__device__ __forceinline__ unsigned short rne16(float f) {
    unsigned u = __float_as_uint(f);
    return (unsigned short)((u + 0x7FFFu + ((u >> 16) & 1u)) >> 16);
}
__device__ __forceinline__ float bf2f(unsigned short h) {
    return __uint_as_float(((unsigned)h) << 16);
}
// interleaved split word: hi bf16 in [31:16], lo bf16 in [15:0]
__device__ __forceinline__ unsigned packsplit(float f) {
    unsigned short hi = rne16(f);
    unsigned short lo = rne16(f - bf2f(hi));
    return ((unsigned)hi << 16) | lo;
}
__device__ __forceinline__ float recon(unsigned u) {
    return __uint_as_float(u & 0xFFFF0000u) + __uint_as_float(u << 16);
}
__device__ __forceinline__ float4 recon4(uint4 u) {
    return make_float4(recon(u.x), recon(u.y), recon(u.z), recon(u.w));
}

// ---------------------------------------------------------------- prep
// v7: ent->Esp split pass DELETED (split format is 32b/elem = fp32 size, so
// it saved no bandwidth; gemm-L0 now splits ent in regs on its idle VALU).
// Fused: [0,eb) count in-degrees; [eb, +32) pack W into MFMA B-fragment
// order (hi/lo planes). B layout (fragment-major, per plane of 16384 shorts):
//   plane[kc*4096 + ct*512 + (quad*16 + l16)*8 + j] = bf16(W[kc*32+quad*8+j][ct*16+l16])
// so a wave's ds_read_b128 for column-tile ct is contiguous 1KB (lane*16B).
__global__ __launch_bounds__(256) void prep_kernel(
    const int* __restrict__ dst, int* __restrict__ deg, int e, int eb,
    const float* __restrict__ Wn, const float* __restrict__ Wl,
    ushort* __restrict__ packW) {
    int b = blockIdx.x;
    if (b < eb) {
        int i = b * 256 + threadIdx.x;
        if (i < e) atomicAdd(&deg[dst[i]], 1);
    } else {
        int t = (b - eb) * 256 + threadIdx.x;
        if (t >= 4 * 4 * 128 * 4) return;
        int quad = t & 3;
        int nn   = (t >> 2) & 127;
        int kc   = (t >> 9) & 3;
        int mat  = t >> 11;   // 0=Wn L0, 1=Wl L0, 2=Wn L1, 3=Wl L1
        const float* W = ((mat & 1) ? Wl : Wn) + (mat >> 1) * 16384;
        ushort* oh = packW + mat * 32768;
        ushort* ol = oh + 16384;
        int obase = kc * 4096 + (nn >> 4) * 512 + (quad * 16 + (nn & 15)) * 8;
        #pragma unroll
        for (int j = 0; j < 8; ++j) {
            float w = W[(kc * 32 + quad * 8 + j) * 128 + nn];
            unsigned short hi = rne16(w);
            oh[obase + j] = hi;
            ol[obase + j] = rne16(w - bf2f(hi));
        }
    }
}

// --- scan: partial block sums, then finalize (aux prefix inlined) ---------
__global__ __launch_bounds__(256) void scan_partial_kernel(const int* __restrict__ deg,
                                                           int* __restrict__ partial, int n) {
    __shared__ int wsum[4];
    int base = blockIdx.x * 1024;
    int t = threadIdx.x;
    int s = 0;
    #pragma unroll
    for (int j = 0; j < 4; ++j) {
        int i = base + t + 256 * j;
        if (i < n) s += deg[i];
    }
    #pragma unroll
    for (int off = 1; off < 64; off <<= 1) s += __shfl_xor(s, off, 64);
    if ((t & 63) == 0) wsum[t >> 6] = s;
    __syncthreads();
    if (t == 0) partial[blockIdx.x] = wsum[0] + wsum[1] + wsum[2] + wsum[3];
}

// exclusive scan finalize (computes own block base from partial[]) +
// alone-node detection (deg==0). Requires nparts <= 64.
__global__ __launch_bounds__(256) void scan_final_kernel(const int* __restrict__ deg,
                                                         const int* __restrict__ partial,
                                                         int* __restrict__ row_off,
                                                         int* __restrict__ alone_list,
                                                         int* __restrict__ alone_count, int n) {
    __shared__ int wsum[4];
    __shared__ int sbase;
    int bid = blockIdx.x;
    int t = threadIdx.x, lane = t & 63, wid = t >> 6;
    if (wid == 0) {
        int v = (lane < bid) ? partial[lane] : 0;
        #pragma unroll
        for (int off = 1; off < 64; off <<= 1) v += __shfl_xor(v, off, 64);
        if (lane == 0) sbase = v;
    }
    int base = bid * 1024;
    int i0 = base + t * 4;
    int v0 = (i0 + 0 < n) ? deg[i0 + 0] : 0;
    int v1 = (i0 + 1 < n) ? deg[i0 + 1] : 0;
    int v2 = (i0 + 2 < n) ? deg[i0 + 2] : 0;
    int v3 = (i0 + 3 < n) ? deg[i0 + 3] : 0;
    int s = v0 + v1 + v2 + v3;
    int x = s;
    #pragma unroll
    for (int off = 1; off < 64; off <<= 1) {
        int y = __shfl_up(x, off, 64);
        if (lane >= off) x += y;
    }
    if (lane == 63) wsum[wid] = x;
    __syncthreads();
    int wbase = 0;
    #pragma unroll
    for (int w = 0; w < 4; ++w) { int ws = wsum[w]; if (w < wid) wbase += ws; }
    int p = sbase + wbase + x - s;
    if (i0 + 0 <= n) row_off[i0 + 0] = p;
    p += v0;
    if (i0 + 1 <= n) row_off[i0 + 1] = p;
    p += v1;
    if (i0 + 2 <= n) row_off[i0 + 2] = p;
    p += v2;
    if (i0 + 3 <= n) row_off[i0 + 3] = p;
    if (i0 + 0 < n && v0 == 0) { int q = atomicAdd(alone_count, 1); if (q < ALONE_CAP) alone_list[q] = i0; }
    if (i0 + 1 < n && v1 == 0) { int q = atomicAdd(alone_count, 1); if (q < ALONE_CAP) alone_list[q] = i0 + 1; }
    if (i0 + 2 < n && v2 == 0) { int q = atomicAdd(alone_count, 1); if (q < ALONE_CAP) alone_list[q] = i0 + 2; }
    if (i0 + 3 < n && v3 == 0) { int q = atomicAdd(alone_count, 1); if (q < ALONE_CAP) alone_list[q] = i0 + 3; }
}

// edges packed as uint: src | (ety << 16). Valid: N_ENTS=50000<2^16, N_RELS=200.
__global__ __launch_bounds__(256) void scatter_kernel(
    const int* __restrict__ src, const int* __restrict__ dst,
    const int* __restrict__ ety, const int* __restrict__ row_off,
    int* __restrict__ cursor, unsigned* __restrict__ edges, int e) {
    int i = blockIdx.x * 256 + threadIdx.x;
    if (i < e) {
        int v = dst[i];
        int pos = row_off[v] + atomicAdd(&cursor[v], 1);
        edges[pos] = (unsigned)src[i] | ((unsigned)ety[i] << 16);
    }
}

// ------------------------------------------------------- per-layer kernels
// S[v] = norm[v] * sum_e (h[src]+rel[et]); emitted interleaved hi/lo (Ssp).
// SPLIT=0: h is fp32 (hf). SPLIT=1: h is interleaved split (hs), reconstruct.
// One wave/node; half-wave/edge; 8 edges in flight per wave. 50K waves ->
// max TLP; L3-BW-bound (~512MB/layer through L3) -- near its ceiling.
template <int SPLIT>
__global__ __launch_bounds__(256) void agg_kernel(
    const float* __restrict__ hf, const unsigned* __restrict__ hs,
    const float* __restrict__ rel,
    const float* __restrict__ norm, const int* __restrict__ row_off,
    const unsigned* __restrict__ edges, unsigned* __restrict__ Ssp, int n) {
    int wave = threadIdx.x >> 6, lane = threadIdx.x & 63;
    int v = blockIdx.x * 4 + wave;
    if (v >= n) return;
    int s0 = row_off[v], s1 = row_off[v + 1];
    float nm = norm[v];
    int half = lane >> 5;
    int c4 = (lane & 31) * 4;
    float4 acc = make_float4(0.f, 0.f, 0.f, 0.f);
    int e = s0;
    for (; e + 7 < s1; e += 8) {
        unsigned q0 = edges[e + half];
        unsigned q1 = edges[e + 2 + half];
        unsigned q2 = edges[e + 4 + half];
        unsigned q3 = edges[e + 6 + half];
        float4 h0, h1, h2, h3;
        if (SPLIT) {
            h0 = recon4(*(const uint4*)&hs[(size_t)(q0 & 0xFFFFu) * 128 + c4]);
            h1 = recon4(*(const uint4*)&hs[(size_t)(q1 & 0xFFFFu) * 128 + c4]);
            h2 = recon4(*(const uint4*)&hs[(size_t)(q2 & 0xFFFFu) * 128 + c4]);
            h3 = recon4(*(const uint4*)&hs[(size_t)(q3 & 0xFFFFu) * 128 + c4]);
        } else {
            h0 = *(const float4*)&hf[(size_t)(q0 & 0xFFFFu) * 128 + c4];
            h1 = *(const float4*)&hf[(size_t)(q1 & 0xFFFFu) * 128 + c4];
            h2 = *(const float4*)&hf[(size_t)(q2 & 0xFFFFu) * 128 + c4];
            h3 = *(const float4*)&hf[(size_t)(q3 & 0xFFFFu) * 128 + c4];
        }
        float4 r0 = *(const float4*)&rel[(size_t)(q0 >> 16) * 128 + c4];
        float4 r1 = *(const float4*)&rel[(size_t)(q1 >> 16) * 128 + c4];
        float4 r2 = *(const float4*)&rel[(size_t)(q2 >> 16) * 128 + c4];
        float4 r3 = *(const float4*)&rel[(size_t)(q3 >> 16) * 128 + c4];
        acc.x += ((h0.x + r0.x) + (h1.x + r1.x)) + ((h2.x + r2.x) + (h3.x + r3.x));
        acc.y += ((h0.y + r0.y) + (h1.y + r1.y)) + ((h2.y + r2.y) + (h3.y + r3.y));
        acc.z += ((h0.z + r0.z) + (h1.z + r1.z)) + ((h2.z + r2.z) + (h3.z + r3.z));
        acc.w += ((h0.w + r0.w) + (h1.w + r1.w)) + ((h2.w + r2.w) + (h3.w + r3.w));
    }
    for (; e + 1 < s1; e += 2) {
        unsigned q0 = edges[e + half];
        float4 h0 = SPLIT ? recon4(*(const uint4*)&hs[(size_t)(q0 & 0xFFFFu) * 128 + c4])
                          : *(const float4*)&hf[(size_t)(q0 & 0xFFFFu) * 128 + c4];
        float4 r0 = *(const float4*)&rel[(size_t)(q0 >> 16) * 128 + c4];
        acc.x += h0.x + r0.x; acc.y += h0.y + r0.y;
        acc.z += h0.z + r0.z; acc.w += h0.w + r0.w;
    }
    if (e < s1 && half == 0) {
        unsigned q0 = edges[e];
        float4 h0 = SPLIT ? recon4(*(const uint4*)&hs[(size_t)(q0 & 0xFFFFu) * 128 + c4])
                          : *(const float4*)&hf[(size_t)(q0 & 0xFFFFu) * 128 + c4];
        float4 r0 = *(const float4*)&rel[(size_t)(q0 >> 16) * 128 + c4];
        acc.x += h0.x + r0.x; acc.y += h0.y + r0.y;
        acc.z += h0.z + r0.z; acc.w += h0.w + r0.w;
    }
    acc.x += __shfl_xor(acc.x, 32, 64);
    acc.y += __shfl_xor(acc.y, 32, 64);
    acc.z += __shfl_xor(acc.z, 32, 64);
    acc.w += __shfl_xor(acc.w, 32, 64);
    if (half == 0) {
        uint4 w;
        w.x = packsplit(acc.x * nm); w.y = packsplit(acc.y * nm);
        w.z = packsplit(acc.z * nm); w.w = packsplit(acc.w * nm);
        *(uint4*)&Ssp[(size_t)v * 128 + c4] = w;
    }
}

// out = leaky(S@Wn + H@Wl) via bf16-split MFMA (3 products).
// Block = 256 thr = 4 waves; wave tile 16 rows x 128 cols; grid ceil(n/64).
// R8 structure (proven): 64KB LDS holds one full matrix; stage Wn -> steps
// 0-3 barrier-free -> barrier -> stage Wl + hoist H (overlapped) -> barrier
// -> steps 4-7 barrier-free. 2 latency exposures, 3 barriers.
// v7: HSPLIT template. HSPLIT=1: H rows are interleaved split (Esp).
// HSPLIT=0: H rows are raw fp32 (ent) -- split to bf16 hi/lo in regs on the
// idle VALU (bit-identical to prep's packsplit); kills the 51MB ent->Esp
// prep pass. Loads unified as uint4 (fp32 bits reinterpreted in consume).
// Alias-safe: each wave reads/writes only its own 16 rows.
template <int HSPLIT>
__global__ __launch_bounds__(256, 2) void gemm_mfma_kernel(
    const unsigned* __restrict__ Ssp, const unsigned* __restrict__ Hw,
    const ushort* __restrict__ Pnh, const ushort* __restrict__ Pnl,
    const ushort* __restrict__ Plh, const ushort* __restrict__ Pll,
    float* __restrict__ out, unsigned* Osp, int n) {
    __shared__ ushort ldsB[4][2][4096];  // [kc][plane hi/lo][8KB] = 64KB

    const int tid = threadIdx.x;
    const int wave = tid >> 6, lane = tid & 63;
    const int quad = lane >> 4, l16 = lane & 15;
    const int row_base = blockIdx.x * 64 + wave * 16;

    int r0c = row_base + l16;
    if (r0c > n - 1) r0c = n - 1;
    const size_t arow = (size_t)r0c * 128;
    const int q8 = quad * 8;

    ffrag acc[8];
    #pragma unroll
    for (int ct = 0; ct < 8; ++ct) acc[ct] = (ffrag)0.f;

    // Stage one full matrix (4 kc-slices, hi+lo) into the 64KB buffer.
    // 16 named loads then 16 ds_writes (16-wide MLP, no spill-prone arrays).
#define STAGE_MAT(PH, PL)                                                        \
    {                                                                            \
        uint4 t00 = *(const uint4*)((PH) + 0 * 4096 + tid * 8);                  \
        uint4 t01 = *(const uint4*)((PH) + 0 * 4096 + 2048 + tid * 8);           \
        uint4 t02 = *(const uint4*)((PL) + 0 * 4096 + tid * 8);                  \
        uint4 t03 = *(const uint4*)((PL) + 0 * 4096 + 2048 + tid * 8);           \
        uint4 t10 = *(const uint4*)((PH) + 1 * 4096 + tid * 8);                  \
        uint4 t11 = *(const uint4*)((PH) + 1 * 4096 + 2048 + tid * 8);           \
        uint4 t12 = *(const uint4*)((PL) + 1 * 4096 + tid * 8);                  \
        uint4 t13 = *(const uint4*)((PL) + 1 * 4096 + 2048 + tid * 8);           \
        uint4 t20 = *(const uint4*)((PH) + 2 * 4096 + tid * 8);                  \
        uint4 t21 = *(const uint4*)((PH) + 2 * 4096 + 2048 + tid * 8);           \
        uint4 t22 = *(const uint4*)((PL) + 2 * 4096 + tid * 8);                  \
        uint4 t23 = *(const uint4*)((PL) + 2 * 4096 + 2048 + tid * 8);           \
        uint4 t30 = *(const uint4*)((PH) + 3 * 4096 + tid * 8);                  \
        uint4 t31 = *(const uint4*)((PH) + 3 * 4096 + 2048 + tid * 8);           \
        uint4 t32 = *(const uint4*)((PL) + 3 * 4096 + tid * 8);                  \
        uint4 t33 = *(const uint4*)((PL) + 3 * 4096 + 2048 + tid * 8);           \
        *(uint4*)&ldsB[0][0][tid * 8] = t00;                                     \
        *(uint4*)&ldsB[0][0][2048 + tid * 8] = t01;                              \
        *(uint4*)&ldsB[0][1][tid * 8] = t02;                                     \
        *(uint4*)&ldsB[0][1][2048 + tid * 8] = t03;                              \
        *(uint4*)&ldsB[1][0][tid * 8] = t10;                                     \
        *(uint4*)&ldsB[1][0][2048 + tid * 8] = t11;                              \
        *(uint4*)&ldsB[1][1][tid * 8] = t12;                                     \
        *(uint4*)&ldsB[1][1][2048 + tid * 8] = t13;                              \
        *(uint4*)&ldsB[2][0][tid * 8] = t20;                                     \
        *(uint4*)&ldsB[2][0][2048 + tid * 8] = t21;                              \
        *(uint4*)&ldsB[2][1][tid * 8] = t22;                                     \
        *(uint4*)&ldsB[2][1][2048 + tid * 8] = t23;                              \
        *(uint4*)&ldsB[3][0][tid * 8] = t30;                                     \
        *(uint4*)&ldsB[3][0][2048 + tid * 8] = t31;                              \
        *(uint4*)&ldsB[3][1][tid * 8] = t32;                                     \
        *(uint4*)&ldsB[3][1][2048 + tid * 8] = t33;                              \
    }

#define GREADB(KC)                                                               \
        bfrag bh[8], bl[8];                                                      \
        _Pragma("unroll")                                                        \
        for (int ct = 0; ct < 8; ++ct) {                                         \
            bh[ct] = *(const bfrag*)&ldsB[KC][0][ct * 512 + lane * 8];           \
            bl[ct] = *(const bfrag*)&ldsB[KC][1][ct * 512 + lane * 8];           \
        }

#define GMFMA3                                                                   \
        _Pragma("unroll")                                                        \
        for (int ct = 0; ct < 8; ++ct)                                           \
            acc[ct] = __builtin_amdgcn_mfma_f32_16x16x32_bf16(ah, bh[ct], acc[ct], 0, 0, 0); \
        _Pragma("unroll")                                                        \
        for (int ct = 0; ct < 8; ++ct)                                           \
            acc[ct] = __builtin_amdgcn_mfma_f32_16x16x32_bf16(ah, bl[ct], acc[ct], 0, 0, 0); \
        _Pragma("unroll")                                                        \
        for (int ct = 0; ct < 8; ++ct)                                           \
            acc[ct] = __builtin_amdgcn_mfma_f32_16x16x32_bf16(al, bh[ct], acc[ct], 0, 0, 0);

    // K-step, A = interleaved split words
#define GSTEP(KC, A0, A1)                                                        \
    {                                                                            \
        GREADB(KC)                                                               \
        bfrag ah, al;                                                            \
        _Pragma("unroll")                                                        \
        for (int j = 0; j < 4; ++j) {                                            \
            unsigned u0 = ((const unsigned*)&(A0))[j];                           \
            unsigned u1 = ((const unsigned*)&(A1))[j];                           \
            ah[j]     = (short)(u0 >> 16); al[j]     = (short)(u0 & 0xFFFFu);    \
            ah[j + 4] = (short)(u1 >> 16); al[j + 4] = (short)(u1 & 0xFFFFu);    \
        }                                                                        \
        GMFMA3                                                                   \
    }

    // K-step, A = fp32 bits (split in regs; identical math to packsplit)
#define GSTEP_F(KC, A0, A1)                                                      \
    {                                                                            \
        GREADB(KC)                                                               \
        bfrag ah, al;                                                            \
        _Pragma("unroll")                                                        \
        for (int j = 0; j < 4; ++j) {                                            \
            float fa = __uint_as_float(((const unsigned*)&(A0))[j]);             \
            float fb = __uint_as_float(((const unsigned*)&(A1))[j]);             \
            unsigned short ha = rne16(fa);                                       \
            unsigned short hb = rne16(fb);                                       \
            ah[j]     = (short)ha; al[j]     = (short)rne16(fa - bf2f(ha));      \
            ah[j + 4] = (short)hb; al[j + 4] = (short)rne16(fb - bf2f(hb));      \
        }                                                                        \
        GMFMA3                                                                   \
    }

    // ---- prologue: S-half A hoist (8 named uint4) + stage Wn; one drain
    uint4 a00 = *(const uint4*)(Ssp + arow + 0 * 32 + q8);
    uint4 a01 = *(const uint4*)(Ssp + arow + 0 * 32 + q8 + 4);
    uint4 a10 = *(const uint4*)(Ssp + arow + 1 * 32 + q8);
    uint4 a11 = *(const uint4*)(Ssp + arow + 1 * 32 + q8 + 4);
    uint4 a20 = *(const uint4*)(Ssp + arow + 2 * 32 + q8);
    uint4 a21 = *(const uint4*)(Ssp + arow + 2 * 32 + q8 + 4);
    uint4 a30 = *(const uint4*)(Ssp + arow + 3 * 32 + q8);
    uint4 a31 = *(const uint4*)(Ssp + arow + 3 * 32 + q8 + 4);
    STAGE_MAT(Pnh, Pnl)
    __syncthreads();  // barrier 1: Wn staged (drains A hoist too)

    GSTEP(0, a00, a01)
    GSTEP(1, a10, a11)
    GSTEP(2, a20, a21)
    GSTEP(3, a30, a31)

    __syncthreads();  // barrier 2: all Wn reads complete

    // ---- midpoint: H-half A hoist + stage Wl; latencies overlap, one drain
    uint4 a40 = *(const uint4*)(Hw + arow + 0 * 32 + q8);
    uint4 a41 = *(const uint4*)(Hw + arow + 0 * 32 + q8 + 4);
    uint4 a50 = *(const uint4*)(Hw + arow + 1 * 32 + q8);
    uint4 a51 = *(const uint4*)(Hw + arow + 1 * 32 + q8 + 4);
    uint4 a60 = *(const uint4*)(Hw + arow + 2 * 32 + q8);
    uint4 a61 = *(const uint4*)(Hw + arow + 2 * 32 + q8 + 4);
    uint4 a70 = *(const uint4*)(Hw + arow + 3 * 32 + q8);
    uint4 a71 = *(const uint4*)(Hw + arow + 3 * 32 + q8 + 4);
    STAGE_MAT(Plh, Pll)
    __syncthreads();  // barrier 3: Wl staged (drains H hoist too)

    if (HSPLIT) {
        GSTEP(0, a40, a41)
        GSTEP(1, a50, a51)
        GSTEP(2, a60, a61)
        GSTEP(3, a70, a71)
    } else {
        GSTEP_F(0, a40, a41)
        GSTEP_F(1, a50, a51)
        GSTEP_F(2, a60, a61)
        GSTEP_F(3, a70, a71)
    }
#undef GSTEP
#undef GSTEP_F
#undef GREADB
#undef GMFMA3
#undef STAGE_MAT

    #pragma unroll
    for (int ct = 0; ct < 8; ++ct) {
        #pragma unroll
        for (int rg = 0; rg < 4; ++rg) {
            int r = row_base + quad * 4 + rg;
            if (r < n) {
                int c = ct * 16 + l16;
                float v = acc[ct][rg];
                v = v >= 0.f ? v : v * SLOPE;
                if (out) out[(size_t)r * 128 + c] = v;
                if (Osp) Osp[(size_t)r * 128 + c] = packsplit(v);
            }
        }
    }
}

// Alone nodes: o = leaky(hrow @ Wa).
// Layer 0 (by_node=1): hrow = ent[v]; writes Osp (h1 split) + asave fp32.
// Layer 1 (by_node=0): hrow = asave[i]; writes out fp32.
__global__ __launch_bounds__(128) void fixup_kernel(
    const float* __restrict__ Hrows, int by_node,
    const float* __restrict__ Wa,
    const int* __restrict__ alone_list, const int* __restrict__ alone_count,
    float* out, unsigned* Osp, float* asave) {
    int cnt = *alone_count;
    if (cnt > ALONE_CAP) cnt = ALONE_CAP;
    int t = threadIdx.x;
    for (int i = blockIdx.x; i < cnt; i += gridDim.x) {
        int v = alone_list[i];
        const float* hrow = Hrows + (size_t)(by_node ? v : i) * 128;
        float acc = 0.f;
        for (int k = 0; k < 128; ++k)
            acc += hrow[k] * Wa[k * 128 + t];
        float o = acc >= 0.f ? acc : acc * SLOPE;
        if (out) out[(size_t)v * 128 + t] = o;
        if (Osp) Osp[(size_t)v * 128 + t] = packsplit(o);
        if (asave) asave[(size_t)i * 128 + t] = o;
    }
}

extern "C" void kernel_launch(void* const* d_in, const int* in_sizes, int n_in,
                              void* d_out, int out_size, void* d_ws, size_t ws_size,
                              hipStream_t stream) {
    const float* ent  = (const float*)d_in[0];
    const float* rel  = (const float*)d_in[1];
    const float* norm = (const float*)d_in[2];
    const float* Wn   = (const float*)d_in[3];
    const float* Wl   = (const float*)d_in[4];
    const float* Wa   = (const float*)d_in[5];
    const int*   src  = (const int*)d_in[6];
    const int*   dst  = (const int*)d_in[7];
    const int*   ety  = (const int*)d_in[8];
    float* out = (float*)d_out;

    const int n = in_sizes[2];   // 50000
    const int e = in_sizes[7];   // 500000

    // workspace layout
    char* ws = (char*)d_ws;
    int* deg         = (int*)ws;          // n
    int* cursor      = deg + n;           // n
    int* alone_count = cursor + n;        // 1
    size_t zbytes = (size_t)(2 * n + 1) * sizeof(int);
    size_t p = (zbytes + 255) & ~(size_t)255;
    int* row_off = (int*)(ws + p);        // n+1
    p += (((size_t)(n + 1) * 4) + 255) & ~(size_t)255;
    int* partial = (int*)(ws + p);        // <=64
    p += 256;
    int* alone_list = (int*)(ws + p);     // ALONE_CAP
    p += (((size_t)ALONE_CAP * 4) + 255) & ~(size_t)255;
    float* asave = (float*)(ws + p);      // ALONE_CAP*128 f32 (1 MB)
    p += (((size_t)ALONE_CAP * 128 * 4) + 255) & ~(size_t)255;
    unsigned* edges = (unsigned*)(ws + p);// e packed (2 MB)
    p += (((size_t)e * 4) + 255) & ~(size_t)255;
    unsigned* Ssp = (unsigned*)(ws + p);  // n*128 interleaved split (25.6 MB)
    p += (((size_t)n * 128 * 4) + 255) & ~(size_t)255;
    unsigned* Esp = (unsigned*)(ws + p);  // h1 split (25.6 MB)
    p += (((size_t)n * 128 * 4) + 255) & ~(size_t)255;
    ushort* packW = (ushort*)(ws + p);    // 4 mats x (hi16K + lo16K) (256 KB)
    p += 4 * 32768 * 2;

    const int eb = (e + 255) / 256;             // 1954
    const int nparts = (n + 1023) / 1024;       // 49 (<=64 required)
    const int gb = (n + 63) / 64;               // 782
    const int ab = (n + 3) / 4;                 // 12500

    hipMemsetAsync(ws, 0, zbytes, stream);
    prep_kernel<<<eb + 32, 256, 0, stream>>>(dst, deg, e, eb, Wn, Wl, packW);
    scan_partial_kernel<<<nparts, 256, 0, stream>>>(deg, partial, n);
    scan_final_kernel<<<nparts, 256, 0, stream>>>(deg, partial, row_off,
                                                  alone_list, alone_count, n);
    scatter_kernel<<<eb, 256, 0, stream>>>(src, dst, ety, row_off, cursor, edges, e);

    // layer 0: agg from ent fp32; gemm H = ent fp32 (in-reg split); out = Esp (h1 split)
    agg_kernel<0><<<ab, 256, 0, stream>>>(ent, nullptr, rel, norm, row_off, edges, Ssp, n);
    gemm_mfma_kernel<0><<<gb, 256, 0, stream>>>(Ssp, (const unsigned*)ent,
                                                packW, packW + 16384,
                                                packW + 32768, packW + 49152,
                                                nullptr, Esp, n);
    fixup_kernel<<<16, 128, 0, stream>>>(ent, 1, Wa, alone_list, alone_count,
                                         nullptr, Esp, asave);

    // layer 1: agg from Esp split; gemm H = Esp split; out = fp32 d_out
    agg_kernel<1><<<ab, 256, 0, stream>>>(nullptr, Esp, rel, norm, row_off, edges, Ssp, n);
    gemm_mfma_kernel<1><<<gb, 256, 0, stream>>>(Ssp, Esp,
                                                packW + 65536, packW + 81920,
                                                packW + 98304, packW + 114688,
                                                out, nullptr, n);
    fixup_kernel<<<16, 128, 0, stream>>>(asave, 0, Wa + 16384, alone_list, alone_count,
                                         out, nullptr, nullptr);
}

// Round 11
// 271.590 us; speedup vs baseline: 1.3144x; 1.0144x over previous
//
#include <hip/hip_runtime.h>

#define SLOPE 0.22916666666666666f  // (1/8 + 1/3) / 2
#define ALONE_CAP 2048              // expected alone nodes ~2.3

typedef __attribute__((ext_vector_type(8))) short bfrag;   // 8 x bf16 bits
typedef __attribute__((ext_vector_type(4))) float ffrag;   // 4 x f32 acc

__device__ __forceinline__ unsigned short rne16(float f) {
    unsigned u = __float_as_uint(f);
    return (unsigned short)((u + 0x7FFFu + ((u >> 16) & 1u)) >> 16);
}
__device__ __forceinline__ float bf2f(unsigned short h) {
    return __uint_as_float(((unsigned)h) << 16);
}
// interleaved split word: hi bf16 in [31:16], lo bf16 in [15:0]
__device__ __forceinline__ unsigned packsplit(float f) {
    unsigned short hi = rne16(f);
    unsigned short lo = rne16(f - bf2f(hi));
    return ((unsigned)hi << 16) | lo;
}
__device__ __forceinline__ float recon(unsigned u) {
    return __uint_as_float(u & 0xFFFF0000u) + __uint_as_float(u << 16);
}
__device__ __forceinline__ float4 recon4(uint4 u) {
    return make_float4(recon(u.x), recon(u.y), recon(u.z), recon(u.w));
}

// ---------------------------------------------------------------- prep
// Fused: [0,eb) count in-degrees; [eb, +32) pack W into MFMA B-fragment
// order (hi/lo planes). B layout (fragment-major, per plane of 16384 shorts):
//   plane[kc*4096 + ct*512 + (quad*16 + l16)*8 + j] = bf16(W[kc*32+quad*8+j][ct*16+l16])
// so a wave's ds_read_b128 for column-tile ct is contiguous 1KB (lane*16B).
__global__ __launch_bounds__(256) void prep_kernel(
    const int* __restrict__ dst, int* __restrict__ deg, int e, int eb,
    const float* __restrict__ Wn, const float* __restrict__ Wl,
    ushort* __restrict__ packW) {
    int b = blockIdx.x;
    if (b < eb) {
        int i = b * 256 + threadIdx.x;
        if (i < e) atomicAdd(&deg[dst[i]], 1);
    } else {
        int t = (b - eb) * 256 + threadIdx.x;
        if (t >= 4 * 4 * 128 * 4) return;
        int quad = t & 3;
        int nn   = (t >> 2) & 127;
        int kc   = (t >> 9) & 3;
        int mat  = t >> 11;   // 0=Wn L0, 1=Wl L0, 2=Wn L1, 3=Wl L1
        const float* W = ((mat & 1) ? Wl : Wn) + (mat >> 1) * 16384;
        ushort* oh = packW + mat * 32768;
        ushort* ol = oh + 16384;
        int obase = kc * 4096 + (nn >> 4) * 512 + (quad * 16 + (nn & 15)) * 8;
        #pragma unroll
        for (int j = 0; j < 8; ++j) {
            float w = W[(kc * 32 + quad * 8 + j) * 128 + nn];
            unsigned short hi = rne16(w);
            oh[obase + j] = hi;
            ol[obase + j] = rne16(w - bf2f(hi));
        }
    }
}

// --- scan: partial block sums, then finalize (aux prefix inlined) ---------
__global__ __launch_bounds__(256) void scan_partial_kernel(const int* __restrict__ deg,
                                                           int* __restrict__ partial, int n) {
    __shared__ int wsum[4];
    int base = blockIdx.x * 1024;
    int t = threadIdx.x;
    int s = 0;
    #pragma unroll
    for (int j = 0; j < 4; ++j) {
        int i = base + t + 256 * j;
        if (i < n) s += deg[i];
    }
    #pragma unroll
    for (int off = 1; off < 64; off <<= 1) s += __shfl_xor(s, off, 64);
    if ((t & 63) == 0) wsum[t >> 6] = s;
    __syncthreads();
    if (t == 0) partial[blockIdx.x] = wsum[0] + wsum[1] + wsum[2] + wsum[3];
}

// exclusive scan finalize (computes own block base from partial[]) +
// alone-node detection (deg==0). Requires nparts <= 64.
__global__ __launch_bounds__(256) void scan_final_kernel(const int* __restrict__ deg,
                                                         const int* __restrict__ partial,
                                                         int* __restrict__ row_off,
                                                         int* __restrict__ alone_list,
                                                         int* __restrict__ alone_count, int n) {
    __shared__ int wsum[4];
    __shared__ int sbase;
    int bid = blockIdx.x;
    int t = threadIdx.x, lane = t & 63, wid = t >> 6;
    if (wid == 0) {
        int v = (lane < bid) ? partial[lane] : 0;
        #pragma unroll
        for (int off = 1; off < 64; off <<= 1) v += __shfl_xor(v, off, 64);
        if (lane == 0) sbase = v;
    }
    int base = bid * 1024;
    int i0 = base + t * 4;
    int v0 = (i0 + 0 < n) ? deg[i0 + 0] : 0;
    int v1 = (i0 + 1 < n) ? deg[i0 + 1] : 0;
    int v2 = (i0 + 2 < n) ? deg[i0 + 2] : 0;
    int v3 = (i0 + 3 < n) ? deg[i0 + 3] : 0;
    int s = v0 + v1 + v2 + v3;
    int x = s;
    #pragma unroll
    for (int off = 1; off < 64; off <<= 1) {
        int y = __shfl_up(x, off, 64);
        if (lane >= off) x += y;
    }
    if (lane == 63) wsum[wid] = x;
    __syncthreads();
    int wbase = 0;
    #pragma unroll
    for (int w = 0; w < 4; ++w) { int ws = wsum[w]; if (w < wid) wbase += ws; }
    int p = sbase + wbase + x - s;
    if (i0 + 0 <= n) row_off[i0 + 0] = p;
    p += v0;
    if (i0 + 1 <= n) row_off[i0 + 1] = p;
    p += v1;
    if (i0 + 2 <= n) row_off[i0 + 2] = p;
    p += v2;
    if (i0 + 3 <= n) row_off[i0 + 3] = p;
    if (i0 + 0 < n && v0 == 0) { int q = atomicAdd(alone_count, 1); if (q < ALONE_CAP) alone_list[q] = i0; }
    if (i0 + 1 < n && v1 == 0) { int q = atomicAdd(alone_count, 1); if (q < ALONE_CAP) alone_list[q] = i0 + 1; }
    if (i0 + 2 < n && v2 == 0) { int q = atomicAdd(alone_count, 1); if (q < ALONE_CAP) alone_list[q] = i0 + 2; }
    if (i0 + 3 < n && v3 == 0) { int q = atomicAdd(alone_count, 1); if (q < ALONE_CAP) alone_list[q] = i0 + 3; }
}

// edges packed as uint: src | (ety << 16). Valid: N_ENTS=50000<2^16, N_RELS=200.
__global__ __launch_bounds__(256) void scatter_kernel(
    const int* __restrict__ src, const int* __restrict__ dst,
    const int* __restrict__ ety, const int* __restrict__ row_off,
    int* __restrict__ cursor, unsigned* __restrict__ edges, int e) {
    int i = blockIdx.x * 256 + threadIdx.x;
    if (i < e) {
        int v = dst[i];
        int pos = row_off[v] + atomicAdd(&cursor[v], 1);
        edges[pos] = (unsigned)src[i] | ((unsigned)ety[i] << 16);
    }
}

// ------------------------------------------------------- per-layer kernels
// S[v] = norm[v] * sum_e (h[src]+rel[et]); emitted interleaved hi/lo (Ssp).
// SPLIT=0: h is fp32 (hf). SPLIT=1: h is interleaved split (hs), reconstruct.
// One wave/node; half-wave/edge; MASKED 8-wide loop (R10 post-mortem: agg at
// 42% HBM / 24% VALU / 62% occ = latency-bound on the 2-wide tail; deg ~
// Poisson(10) so the old deep loop ran ~once then crawled). ALL edges now go
// through ceil(deg/8) full-depth-8 iterations: OOB lanes clamp to the last
// valid edge (reread = L1 hit, ~0 extra traffic) and multiply by a 0/1 mask
// (VALU was 24% busy -- free).
template <int SPLIT>
__global__ __launch_bounds__(256) void agg_kernel(
    const float* __restrict__ hf, const unsigned* __restrict__ hs,
    const float* __restrict__ rel,
    const float* __restrict__ norm, const int* __restrict__ row_off,
    const unsigned* __restrict__ edges, unsigned* __restrict__ Ssp, int n) {
    int wave = threadIdx.x >> 6, lane = threadIdx.x & 63;
    int v = blockIdx.x * 4 + wave;
    if (v >= n) return;
    int s0 = row_off[v], s1 = row_off[v + 1];
    float nm = norm[v];
    int half = lane >> 5;
    int c4 = (lane & 31) * 4;
    float4 acc = make_float4(0.f, 0.f, 0.f, 0.f);
    const int last = s1 - 1;
    for (int e = s0; e < s1; e += 8) {
        const int i0 = e + half;
        const int i1 = e + 2 + half;
        const int i2 = e + 4 + half;
        const int i3 = e + 6 + half;
        unsigned q0 = edges[i0 < s1 ? i0 : last];
        unsigned q1 = edges[i1 < s1 ? i1 : last];
        unsigned q2 = edges[i2 < s1 ? i2 : last];
        unsigned q3 = edges[i3 < s1 ? i3 : last];
        const float m0 = (i0 < s1) ? 1.f : 0.f;
        const float m1 = (i1 < s1) ? 1.f : 0.f;
        const float m2 = (i2 < s1) ? 1.f : 0.f;
        const float m3 = (i3 < s1) ? 1.f : 0.f;
        float4 h0, h1, h2, h3;
        if (SPLIT) {
            h0 = recon4(*(const uint4*)&hs[(size_t)(q0 & 0xFFFFu) * 128 + c4]);
            h1 = recon4(*(const uint4*)&hs[(size_t)(q1 & 0xFFFFu) * 128 + c4]);
            h2 = recon4(*(const uint4*)&hs[(size_t)(q2 & 0xFFFFu) * 128 + c4]);
            h3 = recon4(*(const uint4*)&hs[(size_t)(q3 & 0xFFFFu) * 128 + c4]);
        } else {
            h0 = *(const float4*)&hf[(size_t)(q0 & 0xFFFFu) * 128 + c4];
            h1 = *(const float4*)&hf[(size_t)(q1 & 0xFFFFu) * 128 + c4];
            h2 = *(const float4*)&hf[(size_t)(q2 & 0xFFFFu) * 128 + c4];
            h3 = *(const float4*)&hf[(size_t)(q3 & 0xFFFFu) * 128 + c4];
        }
        float4 r0 = *(const float4*)&rel[(size_t)(q0 >> 16) * 128 + c4];
        float4 r1 = *(const float4*)&rel[(size_t)(q1 >> 16) * 128 + c4];
        float4 r2 = *(const float4*)&rel[(size_t)(q2 >> 16) * 128 + c4];
        float4 r3 = *(const float4*)&rel[(size_t)(q3 >> 16) * 128 + c4];
        acc.x = fmaf(m0, h0.x + r0.x, acc.x);
        acc.y = fmaf(m0, h0.y + r0.y, acc.y);
        acc.z = fmaf(m0, h0.z + r0.z, acc.z);
        acc.w = fmaf(m0, h0.w + r0.w, acc.w);
        acc.x = fmaf(m1, h1.x + r1.x, acc.x);
        acc.y = fmaf(m1, h1.y + r1.y, acc.y);
        acc.z = fmaf(m1, h1.z + r1.z, acc.z);
        acc.w = fmaf(m1, h1.w + r1.w, acc.w);
        acc.x = fmaf(m2, h2.x + r2.x, acc.x);
        acc.y = fmaf(m2, h2.y + r2.y, acc.y);
        acc.z = fmaf(m2, h2.z + r2.z, acc.z);
        acc.w = fmaf(m2, h2.w + r2.w, acc.w);
        acc.x = fmaf(m3, h3.x + r3.x, acc.x);
        acc.y = fmaf(m3, h3.y + r3.y, acc.y);
        acc.z = fmaf(m3, h3.z + r3.z, acc.z);
        acc.w = fmaf(m3, h3.w + r3.w, acc.w);
    }
    acc.x += __shfl_xor(acc.x, 32, 64);
    acc.y += __shfl_xor(acc.y, 32, 64);
    acc.z += __shfl_xor(acc.z, 32, 64);
    acc.w += __shfl_xor(acc.w, 32, 64);
    if (half == 0) {
        uint4 w;
        w.x = packsplit(acc.x * nm); w.y = packsplit(acc.y * nm);
        w.z = packsplit(acc.z * nm); w.w = packsplit(acc.w * nm);
        *(uint4*)&Ssp[(size_t)v * 128 + c4] = w;
    }
}

// out = leaky(S@Wn + H@Wl) via bf16-split MFMA (3 products).
// Block = 256 thr = 4 waves; wave tile 16 rows x 128 cols; grid ceil(n/64).
// R8 structure (proven): 64KB LDS holds one full matrix; stage Wn -> steps
// 0-3 barrier-free -> barrier -> stage Wl + hoist H (overlapped) -> barrier
// -> steps 4-7 barrier-free. 2 latency exposures, 3 barriers.
// HSPLIT=1: H rows are interleaved split (Esp). HSPLIT=0: H rows are raw
// fp32 (ent) -- split to bf16 hi/lo in regs (bit-identical to packsplit).
// Alias-safe: each wave reads/writes only its own 16 rows.
template <int HSPLIT>
__global__ __launch_bounds__(256, 2) void gemm_mfma_kernel(
    const unsigned* __restrict__ Ssp, const unsigned* __restrict__ Hw,
    const ushort* __restrict__ Pnh, const ushort* __restrict__ Pnl,
    const ushort* __restrict__ Plh, const ushort* __restrict__ Pll,
    float* __restrict__ out, unsigned* Osp, int n) {
    __shared__ ushort ldsB[4][2][4096];  // [kc][plane hi/lo][8KB] = 64KB

    const int tid = threadIdx.x;
    const int wave = tid >> 6, lane = tid & 63;
    const int quad = lane >> 4, l16 = lane & 15;
    const int row_base = blockIdx.x * 64 + wave * 16;

    int r0c = row_base + l16;
    if (r0c > n - 1) r0c = n - 1;
    const size_t arow = (size_t)r0c * 128;
    const int q8 = quad * 8;

    ffrag acc[8];
    #pragma unroll
    for (int ct = 0; ct < 8; ++ct) acc[ct] = (ffrag)0.f;

    // Stage one full matrix (4 kc-slices, hi+lo) into the 64KB buffer.
    // 16 named loads then 16 ds_writes (16-wide MLP, no spill-prone arrays).
#define STAGE_MAT(PH, PL)                                                        \
    {                                                                            \
        uint4 t00 = *(const uint4*)((PH) + 0 * 4096 + tid * 8);                  \
        uint4 t01 = *(const uint4*)((PH) + 0 * 4096 + 2048 + tid * 8);           \
        uint4 t02 = *(const uint4*)((PL) + 0 * 4096 + tid * 8);                  \
        uint4 t03 = *(const uint4*)((PL) + 0 * 4096 + 2048 + tid * 8);           \
        uint4 t10 = *(const uint4*)((PH) + 1 * 4096 + tid * 8);                  \
        uint4 t11 = *(const uint4*)((PH) + 1 * 4096 + 2048 + tid * 8);           \
        uint4 t12 = *(const uint4*)((PL) + 1 * 4096 + tid * 8);                  \
        uint4 t13 = *(const uint4*)((PL) + 1 * 4096 + 2048 + tid * 8);           \
        uint4 t20 = *(const uint4*)((PH) + 2 * 4096 + tid * 8);                  \
        uint4 t21 = *(const uint4*)((PH) + 2 * 4096 + 2048 + tid * 8);           \
        uint4 t22 = *(const uint4*)((PL) + 2 * 4096 + tid * 8);                  \
        uint4 t23 = *(const uint4*)((PL) + 2 * 4096 + 2048 + tid * 8);           \
        uint4 t30 = *(const uint4*)((PH) + 3 * 4096 + tid * 8);                  \
        uint4 t31 = *(const uint4*)((PH) + 3 * 4096 + 2048 + tid * 8);           \
        uint4 t32 = *(const uint4*)((PL) + 3 * 4096 + tid * 8);                  \
        uint4 t33 = *(const uint4*)((PL) + 3 * 4096 + 2048 + tid * 8);           \
        *(uint4*)&ldsB[0][0][tid * 8] = t00;                                     \
        *(uint4*)&ldsB[0][0][2048 + tid * 8] = t01;                              \
        *(uint4*)&ldsB[0][1][tid * 8] = t02;                                     \
        *(uint4*)&ldsB[0][1][2048 + tid * 8] = t03;                              \
        *(uint4*)&ldsB[1][0][tid * 8] = t10;                                     \
        *(uint4*)&ldsB[1][0][2048 + tid * 8] = t11;                              \
        *(uint4*)&ldsB[1][1][tid * 8] = t12;                                     \
        *(uint4*)&ldsB[1][1][2048 + tid * 8] = t13;                              \
        *(uint4*)&ldsB[2][0][tid * 8] = t20;                                     \
        *(uint4*)&ldsB[2][0][2048 + tid * 8] = t21;                              \
        *(uint4*)&ldsB[2][1][tid * 8] = t22;                                     \
        *(uint4*)&ldsB[2][1][2048 + tid * 8] = t23;                              \
        *(uint4*)&ldsB[3][0][tid * 8] = t30;                                     \
        *(uint4*)&ldsB[3][0][2048 + tid * 8] = t31;                              \
        *(uint4*)&ldsB[3][1][tid * 8] = t32;                                     \
        *(uint4*)&ldsB[3][1][2048 + tid * 8] = t33;                              \
    }

#define GREADB(KC)                                                               \
        bfrag bh[8], bl[8];                                                      \
        _Pragma("unroll")                                                        \
        for (int ct = 0; ct < 8; ++ct) {                                         \
            bh[ct] = *(const bfrag*)&ldsB[KC][0][ct * 512 + lane * 8];           \
            bl[ct] = *(const bfrag*)&ldsB[KC][1][ct * 512 + lane * 8];           \
        }

#define GMFMA3                                                                   \
        _Pragma("unroll")                                                        \
        for (int ct = 0; ct < 8; ++ct)                                           \
            acc[ct] = __builtin_amdgcn_mfma_f32_16x16x32_bf16(ah, bh[ct], acc[ct], 0, 0, 0); \
        _Pragma("unroll")                                                        \
        for (int ct = 0; ct < 8; ++ct)                                           \
            acc[ct] = __builtin_amdgcn_mfma_f32_16x16x32_bf16(ah, bl[ct], acc[ct], 0, 0, 0); \
        _Pragma("unroll")                                                        \
        for (int ct = 0; ct < 8; ++ct)                                           \
            acc[ct] = __builtin_amdgcn_mfma_f32_16x16x32_bf16(al, bh[ct], acc[ct], 0, 0, 0);

    // K-step, A = interleaved split words
#define GSTEP(KC, A0, A1)                                                        \
    {                                                                            \
        GREADB(KC)                                                               \
        bfrag ah, al;                                                            \
        _Pragma("unroll")                                                        \
        for (int j = 0; j < 4; ++j) {                                            \
            unsigned u0 = ((const unsigned*)&(A0))[j];                           \
            unsigned u1 = ((const unsigned*)&(A1))[j];                           \
            ah[j]     = (short)(u0 >> 16); al[j]     = (short)(u0 & 0xFFFFu);    \
            ah[j + 4] = (short)(u1 >> 16); al[j + 4] = (short)(u1 & 0xFFFFu);    \
        }                                                                        \
        GMFMA3                                                                   \
    }

    // K-step, A = fp32 bits (split in regs; identical math to packsplit)
#define GSTEP_F(KC, A0, A1)                                                      \
    {                                                                            \
        GREADB(KC)                                                               \
        bfrag ah, al;                                                            \
        _Pragma("unroll")                                                        \
        for (int j = 0; j < 4; ++j) {                                            \
            float fa = __uint_as_float(((const unsigned*)&(A0))[j]);             \
            float fb = __uint_as_float(((const unsigned*)&(A1))[j]);             \
            unsigned short ha = rne16(fa);                                       \
            unsigned short hb = rne16(fb);                                       \
            ah[j]     = (short)ha; al[j]     = (short)rne16(fa - bf2f(ha));      \
            ah[j + 4] = (short)hb; al[j + 4] = (short)rne16(fb - bf2f(hb));      \
        }                                                                        \
        GMFMA3                                                                   \
    }

    // ---- prologue: S-half A hoist (8 named uint4) + stage Wn; one drain
    uint4 a00 = *(const uint4*)(Ssp + arow + 0 * 32 + q8);
    uint4 a01 = *(const uint4*)(Ssp + arow + 0 * 32 + q8 + 4);
    uint4 a10 = *(const uint4*)(Ssp + arow + 1 * 32 + q8);
    uint4 a11 = *(const uint4*)(Ssp + arow + 1 * 32 + q8 + 4);
    uint4 a20 = *(const uint4*)(Ssp + arow + 2 * 32 + q8);
    uint4 a21 = *(const uint4*)(Ssp + arow + 2 * 32 + q8 + 4);
    uint4 a30 = *(const uint4*)(Ssp + arow + 3 * 32 + q8);
    uint4 a31 = *(const uint4*)(Ssp + arow + 3 * 32 + q8 + 4);
    STAGE_MAT(Pnh, Pnl)
    __syncthreads();  // barrier 1: Wn staged (drains A hoist too)

    GSTEP(0, a00, a01)
    GSTEP(1, a10, a11)
    GSTEP(2, a20, a21)
    GSTEP(3, a30, a31)

    __syncthreads();  // barrier 2: all Wn reads complete

    // ---- midpoint: H-half A hoist + stage Wl; latencies overlap, one drain
    uint4 a40 = *(const uint4*)(Hw + arow + 0 * 32 + q8);
    uint4 a41 = *(const uint4*)(Hw + arow + 0 * 32 + q8 + 4);
    uint4 a50 = *(const uint4*)(Hw + arow + 1 * 32 + q8);
    uint4 a51 = *(const uint4*)(Hw + arow + 1 * 32 + q8 + 4);
    uint4 a60 = *(const uint4*)(Hw + arow + 2 * 32 + q8);
    uint4 a61 = *(const uint4*)(Hw + arow + 2 * 32 + q8 + 4);
    uint4 a70 = *(const uint4*)(Hw + arow + 3 * 32 + q8);
    uint4 a71 = *(const uint4*)(Hw + arow + 3 * 32 + q8 + 4);
    STAGE_MAT(Plh, Pll)
    __syncthreads();  // barrier 3: Wl staged (drains H hoist too)

    if (HSPLIT) {
        GSTEP(0, a40, a41)
        GSTEP(1, a50, a51)
        GSTEP(2, a60, a61)
        GSTEP(3, a70, a71)
    } else {
        GSTEP_F(0, a40, a41)
        GSTEP_F(1, a50, a51)
        GSTEP_F(2, a60, a61)
        GSTEP_F(3, a70, a71)
    }
#undef GSTEP
#undef GSTEP_F
#undef GREADB
#undef GMFMA3
#undef STAGE_MAT

    #pragma unroll
    for (int ct = 0; ct < 8; ++ct) {
        #pragma unroll
        for (int rg = 0; rg < 4; ++rg) {
            int r = row_base + quad * 4 + rg;
            if (r < n) {
                int c = ct * 16 + l16;
                float v = acc[ct][rg];
                v = v >= 0.f ? v : v * SLOPE;
                if (out) out[(size_t)r * 128 + c] = v;
                if (Osp) Osp[(size_t)r * 128 + c] = packsplit(v);
            }
        }
    }
}

// Alone nodes: o = leaky(hrow @ Wa).
// Layer 0 (by_node=1): hrow = ent[v]; writes Osp (h1 split) + asave fp32.
// Layer 1 (by_node=0): hrow = asave[i]; writes out fp32.
__global__ __launch_bounds__(128) void fixup_kernel(
    const float* __restrict__ Hrows, int by_node,
    const float* __restrict__ Wa,
    const int* __restrict__ alone_list, const int* __restrict__ alone_count,
    float* out, unsigned* Osp, float* asave) {
    int cnt = *alone_count;
    if (cnt > ALONE_CAP) cnt = ALONE_CAP;
    int t = threadIdx.x;
    for (int i = blockIdx.x; i < cnt; i += gridDim.x) {
        int v = alone_list[i];
        const float* hrow = Hrows + (size_t)(by_node ? v : i) * 128;
        float acc = 0.f;
        for (int k = 0; k < 128; ++k)
            acc += hrow[k] * Wa[k * 128 + t];
        float o = acc >= 0.f ? acc : acc * SLOPE;
        if (out) out[(size_t)v * 128 + t] = o;
        if (Osp) Osp[(size_t)v * 128 + t] = packsplit(o);
        if (asave) asave[(size_t)i * 128 + t] = o;
    }
}

extern "C" void kernel_launch(void* const* d_in, const int* in_sizes, int n_in,
                              void* d_out, int out_size, void* d_ws, size_t ws_size,
                              hipStream_t stream) {
    const float* ent  = (const float*)d_in[0];
    const float* rel  = (const float*)d_in[1];
    const float* norm = (const float*)d_in[2];
    const float* Wn   = (const float*)d_in[3];
    const float* Wl   = (const float*)d_in[4];
    const float* Wa   = (const float*)d_in[5];
    const int*   src  = (const int*)d_in[6];
    const int*   dst  = (const int*)d_in[7];
    const int*   ety  = (const int*)d_in[8];
    float* out = (float*)d_out;

    const int n = in_sizes[2];   // 50000
    const int e = in_sizes[7];   // 500000

    // workspace layout
    char* ws = (char*)d_ws;
    int* deg         = (int*)ws;          // n
    int* cursor      = deg + n;           // n
    int* alone_count = cursor + n;        // 1
    size_t zbytes = (size_t)(2 * n + 1) * sizeof(int);
    size_t p = (zbytes + 255) & ~(size_t)255;
    int* row_off = (int*)(ws + p);        // n+1
    p += (((size_t)(n + 1) * 4) + 255) & ~(size_t)255;
    int* partial = (int*)(ws + p);        // <=64
    p += 256;
    int* alone_list = (int*)(ws + p);     // ALONE_CAP
    p += (((size_t)ALONE_CAP * 4) + 255) & ~(size_t)255;
    float* asave = (float*)(ws + p);      // ALONE_CAP*128 f32 (1 MB)
    p += (((size_t)ALONE_CAP * 128 * 4) + 255) & ~(size_t)255;
    unsigned* edges = (unsigned*)(ws + p);// e packed (2 MB)
    p += (((size_t)e * 4) + 255) & ~(size_t)255;
    unsigned* Ssp = (unsigned*)(ws + p);  // n*128 interleaved split (25.6 MB)
    p += (((size_t)n * 128 * 4) + 255) & ~(size_t)255;
    unsigned* Esp = (unsigned*)(ws + p);  // h1 split (25.6 MB)
    p += (((size_t)n * 128 * 4) + 255) & ~(size_t)255;
    ushort* packW = (ushort*)(ws + p);    // 4 mats x (hi16K + lo16K) (256 KB)
    p += 4 * 32768 * 2;

    const int eb = (e + 255) / 256;             // 1954
    const int nparts = (n + 1023) / 1024;       // 49 (<=64 required)
    const int gb = (n + 63) / 64;               // 782
    const int ab = (n + 3) / 4;                 // 12500

    hipMemsetAsync(ws, 0, zbytes, stream);
    prep_kernel<<<eb + 32, 256, 0, stream>>>(dst, deg, e, eb, Wn, Wl, packW);
    scan_partial_kernel<<<nparts, 256, 0, stream>>>(deg, partial, n);
    scan_final_kernel<<<nparts, 256, 0, stream>>>(deg, partial, row_off,
                                                  alone_list, alone_count, n);
    scatter_kernel<<<eb, 256, 0, stream>>>(src, dst, ety, row_off, cursor, edges, e);

    // layer 0: agg from ent fp32; gemm H = ent fp32 (in-reg split); out = Esp (h1 split)
    agg_kernel<0><<<ab, 256, 0, stream>>>(ent, nullptr, rel, norm, row_off, edges, Ssp, n);
    gemm_mfma_kernel<0><<<gb, 256, 0, stream>>>(Ssp, (const unsigned*)ent,
                                                packW, packW + 16384,
                                                packW + 32768, packW + 49152,
                                                nullptr, Esp, n);
    fixup_kernel<<<16, 128, 0, stream>>>(ent, 1, Wa, alone_list, alone_count,
                                         nullptr, Esp, asave);

    // layer 1: agg from Esp split; gemm H = Esp split; out = fp32 d_out
    agg_kernel<1><<<ab, 256, 0, stream>>>(nullptr, Esp, rel, norm, row_off, edges, Ssp, n);
    gemm_mfma_kernel<1><<<gb, 256, 0, stream>>>(Ssp, Esp,
                                                packW + 65536, packW + 81920,
                                                packW + 98304, packW + 114688,
                                                out, nullptr, n);
    fixup_kernel<<<16, 128, 0, stream>>>(asave, 0, Wa + 16384, alone_list, alone_count,
                                         out, nullptr, nullptr);
}

// Round 12
// 267.577 us; speedup vs baseline: 1.3341x; 1.0150x over previous
//
#include <hip/hip_runtime.h>

#define SLOPE 0.22916666666666666f  // (1/8 + 1/3) / 2
#define ALONE_CAP 2048              // expected alone nodes ~2.3

typedef __attribute__((ext_vector_type(8))) short bfrag;   // 8 x bf16 bits
typedef __attribute__((ext_vector_type(4))) float ffrag;   // 4 x f32 acc

__device__ __forceinline__ unsigned short rne16(float f) {
    unsigned u = __float_as_uint(f);
    return (unsigned short)((u + 0x7FFFu + ((u >> 16) & 1u)) >> 16);
}
__device__ __forceinline__ float bf2f(unsigned short h) {
    return __uint_as_float(((unsigned)h) << 16);
}
// interleaved split word: hi bf16 in [31:16], lo bf16 in [15:0]
__device__ __forceinline__ unsigned packsplit(float f) {
    unsigned short hi = rne16(f);
    unsigned short lo = rne16(f - bf2f(hi));
    return ((unsigned)hi << 16) | lo;
}
__device__ __forceinline__ float recon(unsigned u) {
    return __uint_as_float(u & 0xFFFF0000u) + __uint_as_float(u << 16);
}

// ---------------------------------------------------------------- prep
// Fused: [0,eb) count in-degrees; [eb,eb+cb) ent -> pure-bf16 table Eb
// (halves agg gather row 512B->256B; R11 post-mortem: agg is L2-miss-byte
// bound at ~3.3 TB/s); [eb+cb, +32) pack W into MFMA B-fragment order.
// B layout (fragment-major, per plane of 16384 shorts):
//   plane[kc*4096 + ct*512 + (quad*16 + l16)*8 + j] = bf16(W[kc*32+quad*8+j][ct*16+l16])
__global__ __launch_bounds__(256) void prep_kernel(
    const int* __restrict__ dst, int* __restrict__ deg, int e, int eb,
    const float* __restrict__ ent, ushort* __restrict__ Eb,
    int total8, int cb,
    const float* __restrict__ Wn, const float* __restrict__ Wl,
    ushort* __restrict__ packW) {
    int b = blockIdx.x;
    if (b < eb) {
        int i = b * 256 + threadIdx.x;
        if (i < e) atomicAdd(&deg[dst[i]], 1);
    } else if (b < eb + cb) {
        int i = (b - eb) * 256 + threadIdx.x;  // one uint4 = 8 bf16 elems
        if (i >= total8) return;
        float4 v0 = ((const float4*)ent)[i * 2];
        float4 v1 = ((const float4*)ent)[i * 2 + 1];
        uint4 w;
        w.x = (unsigned)rne16(v0.x) | ((unsigned)rne16(v0.y) << 16);
        w.y = (unsigned)rne16(v0.z) | ((unsigned)rne16(v0.w) << 16);
        w.z = (unsigned)rne16(v1.x) | ((unsigned)rne16(v1.y) << 16);
        w.w = (unsigned)rne16(v1.z) | ((unsigned)rne16(v1.w) << 16);
        ((uint4*)Eb)[i] = w;
    } else {
        int t = (b - eb - cb) * 256 + threadIdx.x;
        if (t >= 4 * 4 * 128 * 4) return;
        int quad = t & 3;
        int nn   = (t >> 2) & 127;
        int kc   = (t >> 9) & 3;
        int mat  = t >> 11;   // 0=Wn L0, 1=Wl L0, 2=Wn L1, 3=Wl L1
        const float* W = ((mat & 1) ? Wl : Wn) + (mat >> 1) * 16384;
        ushort* oh = packW + mat * 32768;
        ushort* ol = oh + 16384;
        int obase = kc * 4096 + (nn >> 4) * 512 + (quad * 16 + (nn & 15)) * 8;
        #pragma unroll
        for (int j = 0; j < 8; ++j) {
            float w = W[(kc * 32 + quad * 8 + j) * 128 + nn];
            unsigned short hi = rne16(w);
            oh[obase + j] = hi;
            ol[obase + j] = rne16(w - bf2f(hi));
        }
    }
}

// --- scan: partial block sums, then finalize (aux prefix inlined) ---------
__global__ __launch_bounds__(256) void scan_partial_kernel(const int* __restrict__ deg,
                                                           int* __restrict__ partial, int n) {
    __shared__ int wsum[4];
    int base = blockIdx.x * 1024;
    int t = threadIdx.x;
    int s = 0;
    #pragma unroll
    for (int j = 0; j < 4; ++j) {
        int i = base + t + 256 * j;
        if (i < n) s += deg[i];
    }
    #pragma unroll
    for (int off = 1; off < 64; off <<= 1) s += __shfl_xor(s, off, 64);
    if ((t & 63) == 0) wsum[t >> 6] = s;
    __syncthreads();
    if (t == 0) partial[blockIdx.x] = wsum[0] + wsum[1] + wsum[2] + wsum[3];
}

// exclusive scan finalize (computes own block base from partial[]) +
// alone-node detection (deg==0). Requires nparts <= 64.
__global__ __launch_bounds__(256) void scan_final_kernel(const int* __restrict__ deg,
                                                         const int* __restrict__ partial,
                                                         int* __restrict__ row_off,
                                                         int* __restrict__ alone_list,
                                                         int* __restrict__ alone_count, int n) {
    __shared__ int wsum[4];
    __shared__ int sbase;
    int bid = blockIdx.x;
    int t = threadIdx.x, lane = t & 63, wid = t >> 6;
    if (wid == 0) {
        int v = (lane < bid) ? partial[lane] : 0;
        #pragma unroll
        for (int off = 1; off < 64; off <<= 1) v += __shfl_xor(v, off, 64);
        if (lane == 0) sbase = v;
    }
    int base = bid * 1024;
    int i0 = base + t * 4;
    int v0 = (i0 + 0 < n) ? deg[i0 + 0] : 0;
    int v1 = (i0 + 1 < n) ? deg[i0 + 1] : 0;
    int v2 = (i0 + 2 < n) ? deg[i0 + 2] : 0;
    int v3 = (i0 + 3 < n) ? deg[i0 + 3] : 0;
    int s = v0 + v1 + v2 + v3;
    int x = s;
    #pragma unroll
    for (int off = 1; off < 64; off <<= 1) {
        int y = __shfl_up(x, off, 64);
        if (lane >= off) x += y;
    }
    if (lane == 63) wsum[wid] = x;
    __syncthreads();
    int wbase = 0;
    #pragma unroll
    for (int w = 0; w < 4; ++w) { int ws = wsum[w]; if (w < wid) wbase += ws; }
    int p = sbase + wbase + x - s;
    if (i0 + 0 <= n) row_off[i0 + 0] = p;
    p += v0;
    if (i0 + 1 <= n) row_off[i0 + 1] = p;
    p += v1;
    if (i0 + 2 <= n) row_off[i0 + 2] = p;
    p += v2;
    if (i0 + 3 <= n) row_off[i0 + 3] = p;
    if (i0 + 0 < n && v0 == 0) { int q = atomicAdd(alone_count, 1); if (q < ALONE_CAP) alone_list[q] = i0; }
    if (i0 + 1 < n && v1 == 0) { int q = atomicAdd(alone_count, 1); if (q < ALONE_CAP) alone_list[q] = i0 + 1; }
    if (i0 + 2 < n && v2 == 0) { int q = atomicAdd(alone_count, 1); if (q < ALONE_CAP) alone_list[q] = i0 + 2; }
    if (i0 + 3 < n && v3 == 0) { int q = atomicAdd(alone_count, 1); if (q < ALONE_CAP) alone_list[q] = i0 + 3; }
}

// edges packed as uint: src | (ety << 16). Valid: N_ENTS=50000<2^16, N_RELS=200.
__global__ __launch_bounds__(256) void scatter_kernel(
    const int* __restrict__ src, const int* __restrict__ dst,
    const int* __restrict__ ety, const int* __restrict__ row_off,
    int* __restrict__ cursor, unsigned* __restrict__ edges, int e) {
    int i = blockIdx.x * 256 + threadIdx.x;
    if (i < e) {
        int v = dst[i];
        int pos = row_off[v] + atomicAdd(&cursor[v], 1);
        edges[pos] = (unsigned)src[i] | ((unsigned)ety[i] << 16);
    }
}

// ------------------------------------------------------- per-layer kernels
// S[v] = norm[v] * sum_e (h[src]+rel[et]); emitted interleaved hi/lo (Ssp).
// h gathered from PURE-BF16 table hb (256B/row -- halves L2-miss bytes, the
// R11-measured bottleneck at ~3.3 TB/s miss BW). Sum still fp32; rel fp32
// (L2-hot, not part of miss traffic). Masked 8-wide loop.
__global__ __launch_bounds__(256) void agg_kernel(
    const ushort* __restrict__ hb, const float* __restrict__ rel,
    const float* __restrict__ norm, const int* __restrict__ row_off,
    const unsigned* __restrict__ edges, unsigned* __restrict__ Ssp, int n) {
    int wave = threadIdx.x >> 6, lane = threadIdx.x & 63;
    int v = blockIdx.x * 4 + wave;
    if (v >= n) return;
    int s0 = row_off[v], s1 = row_off[v + 1];
    float nm = norm[v];
    int half = lane >> 5;
    int c4 = (lane & 31) * 4;
    float4 acc = make_float4(0.f, 0.f, 0.f, 0.f);
    const int last = s1 - 1;
    for (int e = s0; e < s1; e += 8) {
        const int i0 = e + half;
        const int i1 = e + 2 + half;
        const int i2 = e + 4 + half;
        const int i3 = e + 6 + half;
        unsigned q0 = edges[i0 < s1 ? i0 : last];
        unsigned q1 = edges[i1 < s1 ? i1 : last];
        unsigned q2 = edges[i2 < s1 ? i2 : last];
        unsigned q3 = edges[i3 < s1 ? i3 : last];
        const float m0 = (i0 < s1) ? 1.f : 0.f;
        const float m1 = (i1 < s1) ? 1.f : 0.f;
        const float m2 = (i2 < s1) ? 1.f : 0.f;
        const float m3 = (i3 < s1) ? 1.f : 0.f;
        ushort4 u0 = *(const ushort4*)&hb[(size_t)(q0 & 0xFFFFu) * 128 + c4];
        ushort4 u1 = *(const ushort4*)&hb[(size_t)(q1 & 0xFFFFu) * 128 + c4];
        ushort4 u2 = *(const ushort4*)&hb[(size_t)(q2 & 0xFFFFu) * 128 + c4];
        ushort4 u3 = *(const ushort4*)&hb[(size_t)(q3 & 0xFFFFu) * 128 + c4];
        float4 r0 = *(const float4*)&rel[(size_t)(q0 >> 16) * 128 + c4];
        float4 r1 = *(const float4*)&rel[(size_t)(q1 >> 16) * 128 + c4];
        float4 r2 = *(const float4*)&rel[(size_t)(q2 >> 16) * 128 + c4];
        float4 r3 = *(const float4*)&rel[(size_t)(q3 >> 16) * 128 + c4];
        acc.x = fmaf(m0, bf2f(u0.x) + r0.x, acc.x);
        acc.y = fmaf(m0, bf2f(u0.y) + r0.y, acc.y);
        acc.z = fmaf(m0, bf2f(u0.z) + r0.z, acc.z);
        acc.w = fmaf(m0, bf2f(u0.w) + r0.w, acc.w);
        acc.x = fmaf(m1, bf2f(u1.x) + r1.x, acc.x);
        acc.y = fmaf(m1, bf2f(u1.y) + r1.y, acc.y);
        acc.z = fmaf(m1, bf2f(u1.z) + r1.z, acc.z);
        acc.w = fmaf(m1, bf2f(u1.w) + r1.w, acc.w);
        acc.x = fmaf(m2, bf2f(u2.x) + r2.x, acc.x);
        acc.y = fmaf(m2, bf2f(u2.y) + r2.y, acc.y);
        acc.z = fmaf(m2, bf2f(u2.z) + r2.z, acc.z);
        acc.w = fmaf(m2, bf2f(u2.w) + r2.w, acc.w);
        acc.x = fmaf(m3, bf2f(u3.x) + r3.x, acc.x);
        acc.y = fmaf(m3, bf2f(u3.y) + r3.y, acc.y);
        acc.z = fmaf(m3, bf2f(u3.z) + r3.z, acc.z);
        acc.w = fmaf(m3, bf2f(u3.w) + r3.w, acc.w);
    }
    acc.x += __shfl_xor(acc.x, 32, 64);
    acc.y += __shfl_xor(acc.y, 32, 64);
    acc.z += __shfl_xor(acc.z, 32, 64);
    acc.w += __shfl_xor(acc.w, 32, 64);
    if (half == 0) {
        uint4 w;
        w.x = packsplit(acc.x * nm); w.y = packsplit(acc.y * nm);
        w.z = packsplit(acc.z * nm); w.w = packsplit(acc.w * nm);
        *(uint4*)&Ssp[(size_t)v * 128 + c4] = w;
    }
}

// out = leaky(S@Wn + H@Wl) via bf16-split MFMA (3 products).
// Block = 256 thr = 4 waves; wave tile 16 rows x 128 cols; grid ceil(n/64).
// R8 structure (proven): 64KB LDS holds one full matrix; stage Wn -> steps
// 0-3 barrier-free -> barrier -> stage Wl + hoist H (overlapped) -> barrier
// -> steps 4-7 barrier-free. 2 latency exposures, 3 barriers.
// HSPLIT=1: H rows are interleaved split (Esp). HSPLIT=0: H rows are raw
// fp32 (ent) -- split to bf16 hi/lo in regs (bit-identical to packsplit).
// Epilogue optionally also emits pure-bf16 rows (Ob16) for the next layer's
// gather. Alias-safe: each wave reads/writes only its own 16 rows.
template <int HSPLIT>
__global__ __launch_bounds__(256, 2) void gemm_mfma_kernel(
    const unsigned* __restrict__ Ssp, const unsigned* __restrict__ Hw,
    const ushort* __restrict__ Pnh, const ushort* __restrict__ Pnl,
    const ushort* __restrict__ Plh, const ushort* __restrict__ Pll,
    float* __restrict__ out, unsigned* Osp, ushort* Ob16, int n) {
    __shared__ ushort ldsB[4][2][4096];  // [kc][plane hi/lo][8KB] = 64KB

    const int tid = threadIdx.x;
    const int wave = tid >> 6, lane = tid & 63;
    const int quad = lane >> 4, l16 = lane & 15;
    const int row_base = blockIdx.x * 64 + wave * 16;

    int r0c = row_base + l16;
    if (r0c > n - 1) r0c = n - 1;
    const size_t arow = (size_t)r0c * 128;
    const int q8 = quad * 8;

    ffrag acc[8];
    #pragma unroll
    for (int ct = 0; ct < 8; ++ct) acc[ct] = (ffrag)0.f;

    // Stage one full matrix (4 kc-slices, hi+lo) into the 64KB buffer.
    // 16 named loads then 16 ds_writes (16-wide MLP, no spill-prone arrays).
#define STAGE_MAT(PH, PL)                                                        \
    {                                                                            \
        uint4 t00 = *(const uint4*)((PH) + 0 * 4096 + tid * 8);                  \
        uint4 t01 = *(const uint4*)((PH) + 0 * 4096 + 2048 + tid * 8);           \
        uint4 t02 = *(const uint4*)((PL) + 0 * 4096 + tid * 8);                  \
        uint4 t03 = *(const uint4*)((PL) + 0 * 4096 + 2048 + tid * 8);           \
        uint4 t10 = *(const uint4*)((PH) + 1 * 4096 + tid * 8);                  \
        uint4 t11 = *(const uint4*)((PH) + 1 * 4096 + 2048 + tid * 8);           \
        uint4 t12 = *(const uint4*)((PL) + 1 * 4096 + tid * 8);                  \
        uint4 t13 = *(const uint4*)((PL) + 1 * 4096 + 2048 + tid * 8);           \
        uint4 t20 = *(const uint4*)((PH) + 2 * 4096 + tid * 8);                  \
        uint4 t21 = *(const uint4*)((PH) + 2 * 4096 + 2048 + tid * 8);           \
        uint4 t22 = *(const uint4*)((PL) + 2 * 4096 + tid * 8);                  \
        uint4 t23 = *(const uint4*)((PL) + 2 * 4096 + 2048 + tid * 8);           \
        uint4 t30 = *(const uint4*)((PH) + 3 * 4096 + tid * 8);                  \
        uint4 t31 = *(const uint4*)((PH) + 3 * 4096 + 2048 + tid * 8);           \
        uint4 t32 = *(const uint4*)((PL) + 3 * 4096 + tid * 8);                  \
        uint4 t33 = *(const uint4*)((PL) + 3 * 4096 + 2048 + tid * 8);           \
        *(uint4*)&ldsB[0][0][tid * 8] = t00;                                     \
        *(uint4*)&ldsB[0][0][2048 + tid * 8] = t01;                              \
        *(uint4*)&ldsB[0][1][tid * 8] = t02;                                     \
        *(uint4*)&ldsB[0][1][2048 + tid * 8] = t03;                              \
        *(uint4*)&ldsB[1][0][tid * 8] = t10;                                     \
        *(uint4*)&ldsB[1][0][2048 + tid * 8] = t11;                              \
        *(uint4*)&ldsB[1][1][tid * 8] = t12;                                     \
        *(uint4*)&ldsB[1][1][2048 + tid * 8] = t13;                              \
        *(uint4*)&ldsB[2][0][tid * 8] = t20;                                     \
        *(uint4*)&ldsB[2][0][2048 + tid * 8] = t21;                              \
        *(uint4*)&ldsB[2][1][tid * 8] = t22;                                     \
        *(uint4*)&ldsB[2][1][2048 + tid * 8] = t23;                              \
        *(uint4*)&ldsB[3][0][tid * 8] = t30;                                     \
        *(uint4*)&ldsB[3][0][2048 + tid * 8] = t31;                              \
        *(uint4*)&ldsB[3][1][tid * 8] = t32;                                     \
        *(uint4*)&ldsB[3][1][2048 + tid * 8] = t33;                              \
    }

#define GREADB(KC)                                                               \
        bfrag bh[8], bl[8];                                                      \
        _Pragma("unroll")                                                        \
        for (int ct = 0; ct < 8; ++ct) {                                         \
            bh[ct] = *(const bfrag*)&ldsB[KC][0][ct * 512 + lane * 8];           \
            bl[ct] = *(const bfrag*)&ldsB[KC][1][ct * 512 + lane * 8];           \
        }

#define GMFMA3                                                                   \
        _Pragma("unroll")                                                        \
        for (int ct = 0; ct < 8; ++ct)                                           \
            acc[ct] = __builtin_amdgcn_mfma_f32_16x16x32_bf16(ah, bh[ct], acc[ct], 0, 0, 0); \
        _Pragma("unroll")                                                        \
        for (int ct = 0; ct < 8; ++ct)                                           \
            acc[ct] = __builtin_amdgcn_mfma_f32_16x16x32_bf16(ah, bl[ct], acc[ct], 0, 0, 0); \
        _Pragma("unroll")                                                        \
        for (int ct = 0; ct < 8; ++ct)                                           \
            acc[ct] = __builtin_amdgcn_mfma_f32_16x16x32_bf16(al, bh[ct], acc[ct], 0, 0, 0);

    // K-step, A = interleaved split words
#define GSTEP(KC, A0, A1)                                                        \
    {                                                                            \
        GREADB(KC)                                                               \
        bfrag ah, al;                                                            \
        _Pragma("unroll")                                                        \
        for (int j = 0; j < 4; ++j) {                                            \
            unsigned u0 = ((const unsigned*)&(A0))[j];                           \
            unsigned u1 = ((const unsigned*)&(A1))[j];                           \
            ah[j]     = (short)(u0 >> 16); al[j]     = (short)(u0 & 0xFFFFu);    \
            ah[j + 4] = (short)(u1 >> 16); al[j + 4] = (short)(u1 & 0xFFFFu);    \
        }                                                                        \
        GMFMA3                                                                   \
    }

    // K-step, A = fp32 bits (split in regs; identical math to packsplit)
#define GSTEP_F(KC, A0, A1)                                                      \
    {                                                                            \
        GREADB(KC)                                                               \
        bfrag ah, al;                                                            \
        _Pragma("unroll")                                                        \
        for (int j = 0; j < 4; ++j) {                                            \
            float fa = __uint_as_float(((const unsigned*)&(A0))[j]);             \
            float fb = __uint_as_float(((const unsigned*)&(A1))[j]);             \
            unsigned short ha = rne16(fa);                                       \
            unsigned short hb = rne16(fb);                                       \
            ah[j]     = (short)ha; al[j]     = (short)rne16(fa - bf2f(ha));      \
            ah[j + 4] = (short)hb; al[j + 4] = (short)rne16(fb - bf2f(hb));      \
        }                                                                        \
        GMFMA3                                                                   \
    }

    // ---- prologue: S-half A hoist (8 named uint4) + stage Wn; one drain
    uint4 a00 = *(const uint4*)(Ssp + arow + 0 * 32 + q8);
    uint4 a01 = *(const uint4*)(Ssp + arow + 0 * 32 + q8 + 4);
    uint4 a10 = *(const uint4*)(Ssp + arow + 1 * 32 + q8);
    uint4 a11 = *(const uint4*)(Ssp + arow + 1 * 32 + q8 + 4);
    uint4 a20 = *(const uint4*)(Ssp + arow + 2 * 32 + q8);
    uint4 a21 = *(const uint4*)(Ssp + arow + 2 * 32 + q8 + 4);
    uint4 a30 = *(const uint4*)(Ssp + arow + 3 * 32 + q8);
    uint4 a31 = *(const uint4*)(Ssp + arow + 3 * 32 + q8 + 4);
    STAGE_MAT(Pnh, Pnl)
    __syncthreads();  // barrier 1: Wn staged (drains A hoist too)

    GSTEP(0, a00, a01)
    GSTEP(1, a10, a11)
    GSTEP(2, a20, a21)
    GSTEP(3, a30, a31)

    __syncthreads();  // barrier 2: all Wn reads complete

    // ---- midpoint: H-half A hoist + stage Wl; latencies overlap, one drain
    uint4 a40 = *(const uint4*)(Hw + arow + 0 * 32 + q8);
    uint4 a41 = *(const uint4*)(Hw + arow + 0 * 32 + q8 + 4);
    uint4 a50 = *(const uint4*)(Hw + arow + 1 * 32 + q8);
    uint4 a51 = *(const uint4*)(Hw + arow + 1 * 32 + q8 + 4);
    uint4 a60 = *(const uint4*)(Hw + arow + 2 * 32 + q8);
    uint4 a61 = *(const uint4*)(Hw + arow + 2 * 32 + q8 + 4);
    uint4 a70 = *(const uint4*)(Hw + arow + 3 * 32 + q8);
    uint4 a71 = *(const uint4*)(Hw + arow + 3 * 32 + q8 + 4);
    STAGE_MAT(Plh, Pll)
    __syncthreads();  // barrier 3: Wl staged (drains H hoist too)

    if (HSPLIT) {
        GSTEP(0, a40, a41)
        GSTEP(1, a50, a51)
        GSTEP(2, a60, a61)
        GSTEP(3, a70, a71)
    } else {
        GSTEP_F(0, a40, a41)
        GSTEP_F(1, a50, a51)
        GSTEP_F(2, a60, a61)
        GSTEP_F(3, a70, a71)
    }
#undef GSTEP
#undef GSTEP_F
#undef GREADB
#undef GMFMA3
#undef STAGE_MAT

    #pragma unroll
    for (int ct = 0; ct < 8; ++ct) {
        #pragma unroll
        for (int rg = 0; rg < 4; ++rg) {
            int r = row_base + quad * 4 + rg;
            if (r < n) {
                int c = ct * 16 + l16;
                float v = acc[ct][rg];
                v = v >= 0.f ? v : v * SLOPE;
                if (out) out[(size_t)r * 128 + c] = v;
                if (Osp) Osp[(size_t)r * 128 + c] = packsplit(v);
                if (Ob16) Ob16[(size_t)r * 128 + c] = rne16(v);
            }
        }
    }
}

// Alone nodes: o = leaky(hrow @ Wa).
// Layer 0 (by_node=1): hrow = ent[v]; writes Osp + Ob16 (h1) + asave fp32.
// Layer 1 (by_node=0): hrow = asave[i]; writes out fp32.
__global__ __launch_bounds__(128) void fixup_kernel(
    const float* __restrict__ Hrows, int by_node,
    const float* __restrict__ Wa,
    const int* __restrict__ alone_list, const int* __restrict__ alone_count,
    float* out, unsigned* Osp, ushort* Ob16, float* asave) {
    int cnt = *alone_count;
    if (cnt > ALONE_CAP) cnt = ALONE_CAP;
    int t = threadIdx.x;
    for (int i = blockIdx.x; i < cnt; i += gridDim.x) {
        int v = alone_list[i];
        const float* hrow = Hrows + (size_t)(by_node ? v : i) * 128;
        float acc = 0.f;
        for (int k = 0; k < 128; ++k)
            acc += hrow[k] * Wa[k * 128 + t];
        float o = acc >= 0.f ? acc : acc * SLOPE;
        if (out) out[(size_t)v * 128 + t] = o;
        if (Osp) Osp[(size_t)v * 128 + t] = packsplit(o);
        if (Ob16) Ob16[(size_t)v * 128 + t] = rne16(o);
        if (asave) asave[(size_t)i * 128 + t] = o;
    }
}

extern "C" void kernel_launch(void* const* d_in, const int* in_sizes, int n_in,
                              void* d_out, int out_size, void* d_ws, size_t ws_size,
                              hipStream_t stream) {
    const float* ent  = (const float*)d_in[0];
    const float* rel  = (const float*)d_in[1];
    const float* norm = (const float*)d_in[2];
    const float* Wn   = (const float*)d_in[3];
    const float* Wl   = (const float*)d_in[4];
    const float* Wa   = (const float*)d_in[5];
    const int*   src  = (const int*)d_in[6];
    const int*   dst  = (const int*)d_in[7];
    const int*   ety  = (const int*)d_in[8];
    float* out = (float*)d_out;

    const int n = in_sizes[2];   // 50000
    const int e = in_sizes[7];   // 500000

    // workspace layout
    char* ws = (char*)d_ws;
    int* deg         = (int*)ws;          // n
    int* cursor      = deg + n;           // n
    int* alone_count = cursor + n;        // 1
    size_t zbytes = (size_t)(2 * n + 1) * sizeof(int);
    size_t p = (zbytes + 255) & ~(size_t)255;
    int* row_off = (int*)(ws + p);        // n+1
    p += (((size_t)(n + 1) * 4) + 255) & ~(size_t)255;
    int* partial = (int*)(ws + p);        // <=64
    p += 256;
    int* alone_list = (int*)(ws + p);     // ALONE_CAP
    p += (((size_t)ALONE_CAP * 4) + 255) & ~(size_t)255;
    float* asave = (float*)(ws + p);      // ALONE_CAP*128 f32 (1 MB)
    p += (((size_t)ALONE_CAP * 128 * 4) + 255) & ~(size_t)255;
    unsigned* edges = (unsigned*)(ws + p);// e packed (2 MB)
    p += (((size_t)e * 4) + 255) & ~(size_t)255;
    unsigned* Ssp = (unsigned*)(ws + p);  // n*128 interleaved split (25.6 MB)
    p += (((size_t)n * 128 * 4) + 255) & ~(size_t)255;
    unsigned* Esp = (unsigned*)(ws + p);  // h1 split (25.6 MB)
    p += (((size_t)n * 128 * 4) + 255) & ~(size_t)255;
    ushort* Eb0 = (ushort*)(ws + p);      // ent bf16 table (12.8 MB)
    p += (((size_t)n * 128 * 2) + 255) & ~(size_t)255;
    ushort* Eb1 = (ushort*)(ws + p);      // h1 bf16 table (12.8 MB)
    p += (((size_t)n * 128 * 2) + 255) & ~(size_t)255;
    ushort* packW = (ushort*)(ws + p);    // 4 mats x (hi16K + lo16K) (256 KB)
    p += 4 * 32768 * 2;

    const int eb = (e + 255) / 256;             // 1954
    const int cb = (n * 16 + 255) / 256;        // 3125 (uint4 = 8 elems)
    const int nparts = (n + 1023) / 1024;       // 49 (<=64 required)
    const int gb = (n + 63) / 64;               // 782
    const int ab = (n + 3) / 4;                 // 12500

    hipMemsetAsync(ws, 0, zbytes, stream);
    prep_kernel<<<eb + cb + 32, 256, 0, stream>>>(dst, deg, e, eb,
                                                  ent, Eb0, n * 16, cb,
                                                  Wn, Wl, packW);
    scan_partial_kernel<<<nparts, 256, 0, stream>>>(deg, partial, n);
    scan_final_kernel<<<nparts, 256, 0, stream>>>(deg, partial, row_off,
                                                  alone_list, alone_count, n);
    scatter_kernel<<<eb, 256, 0, stream>>>(src, dst, ety, row_off, cursor, edges, e);

    // layer 0: agg gathers bf16 ent (Eb0); gemm H = ent fp32 (in-reg split);
    // outputs: Esp (split, for gemm-1 H) + Eb1 (bf16, for agg-1 gather)
    agg_kernel<<<ab, 256, 0, stream>>>(Eb0, rel, norm, row_off, edges, Ssp, n);
    gemm_mfma_kernel<0><<<gb, 256, 0, stream>>>(Ssp, (const unsigned*)ent,
                                                packW, packW + 16384,
                                                packW + 32768, packW + 49152,
                                                nullptr, Esp, Eb1, n);
    fixup_kernel<<<16, 128, 0, stream>>>(ent, 1, Wa, alone_list, alone_count,
                                         nullptr, Esp, Eb1, asave);

    // layer 1: agg gathers bf16 h1 (Eb1); gemm H = Esp split; out = fp32 d_out
    agg_kernel<<<ab, 256, 0, stream>>>(Eb1, rel, norm, row_off, edges, Ssp, n);
    gemm_mfma_kernel<1><<<gb, 256, 0, stream>>>(Ssp, Esp,
                                                packW + 65536, packW + 81920,
                                                packW + 98304, packW + 114688,
                                                out, nullptr, nullptr, n);
    fixup_kernel<<<16, 128, 0, stream>>>(asave, 0, Wa + 16384, alone_list, alone_count,
                                         out, nullptr, nullptr, nullptr);
}

// Round 13
// 256.250 us; speedup vs baseline: 1.3930x; 1.0442x over previous
//
#include <hip/hip_runtime.h>

#define SLOPE 0.22916666666666666f  // (1/8 + 1/3) / 2
#define ALONE_CAP 2048              // expected alone nodes ~2.3

typedef __attribute__((ext_vector_type(8))) short bfrag;   // 8 x bf16 bits
typedef __attribute__((ext_vector_type(4))) float ffrag;   // 4 x f32 acc

__device__ __forceinline__ unsigned short rne16(float f) {
    unsigned u = __float_as_uint(f);
    return (unsigned short)((u + 0x7FFFu + ((u >> 16) & 1u)) >> 16);
}
__device__ __forceinline__ float bf2f(unsigned short h) {
    return __uint_as_float(((unsigned)h) << 16);
}
// interleaved split word: hi bf16 in [31:16], lo bf16 in [15:0]
__device__ __forceinline__ unsigned packsplit(float f) {
    unsigned short hi = rne16(f);
    unsigned short lo = rne16(f - bf2f(hi));
    return ((unsigned)hi << 16) | lo;
}

// ---------------------------------------------------------------- prep
// Fused: [0,eb) count in-degrees; [eb,eb+cb) ent -> pure-bf16 table Eb0
// (256B gather rows; R11/R12: agg is L2-miss-byte bound); [eb+cb, +32)
// pack W into MFMA B-fragment order (hi/lo planes).
// B layout (fragment-major, per plane of 16384 shorts):
//   plane[kc*4096 + ct*512 + (quad*16 + l16)*8 + j] = bf16(W[kc*32+quad*8+j][ct*16+l16])
__global__ __launch_bounds__(256) void prep_kernel(
    const int* __restrict__ dst, int* __restrict__ deg, int e, int eb,
    const float* __restrict__ ent, ushort* __restrict__ Eb,
    int total8, int cb,
    const float* __restrict__ Wn, const float* __restrict__ Wl,
    ushort* __restrict__ packW) {
    int b = blockIdx.x;
    if (b < eb) {
        int i = b * 256 + threadIdx.x;
        if (i < e) atomicAdd(&deg[dst[i]], 1);
    } else if (b < eb + cb) {
        int i = (b - eb) * 256 + threadIdx.x;  // one uint4 = 8 bf16 elems
        if (i >= total8) return;
        float4 v0 = ((const float4*)ent)[i * 2];
        float4 v1 = ((const float4*)ent)[i * 2 + 1];
        uint4 w;
        w.x = (unsigned)rne16(v0.x) | ((unsigned)rne16(v0.y) << 16);
        w.y = (unsigned)rne16(v0.z) | ((unsigned)rne16(v0.w) << 16);
        w.z = (unsigned)rne16(v1.x) | ((unsigned)rne16(v1.y) << 16);
        w.w = (unsigned)rne16(v1.z) | ((unsigned)rne16(v1.w) << 16);
        ((uint4*)Eb)[i] = w;
    } else {
        int t = (b - eb - cb) * 256 + threadIdx.x;
        if (t >= 4 * 4 * 128 * 4) return;
        int quad = t & 3;
        int nn   = (t >> 2) & 127;
        int kc   = (t >> 9) & 3;
        int mat  = t >> 11;   // 0=Wn L0, 1=Wl L0, 2=Wn L1, 3=Wl L1
        const float* W = ((mat & 1) ? Wl : Wn) + (mat >> 1) * 16384;
        ushort* oh = packW + mat * 32768;
        ushort* ol = oh + 16384;
        int obase = kc * 4096 + (nn >> 4) * 512 + (quad * 16 + (nn & 15)) * 8;
        #pragma unroll
        for (int j = 0; j < 8; ++j) {
            float w = W[(kc * 32 + quad * 8 + j) * 128 + nn];
            unsigned short hi = rne16(w);
            oh[obase + j] = hi;
            ol[obase + j] = rne16(w - bf2f(hi));
        }
    }
}

// --- scan: partial block sums, then finalize (aux prefix inlined) ---------
__global__ __launch_bounds__(256) void scan_partial_kernel(const int* __restrict__ deg,
                                                           int* __restrict__ partial, int n) {
    __shared__ int wsum[4];
    int base = blockIdx.x * 1024;
    int t = threadIdx.x;
    int s = 0;
    #pragma unroll
    for (int j = 0; j < 4; ++j) {
        int i = base + t + 256 * j;
        if (i < n) s += deg[i];
    }
    #pragma unroll
    for (int off = 1; off < 64; off <<= 1) s += __shfl_xor(s, off, 64);
    if ((t & 63) == 0) wsum[t >> 6] = s;
    __syncthreads();
    if (t == 0) partial[blockIdx.x] = wsum[0] + wsum[1] + wsum[2] + wsum[3];
}

// exclusive scan finalize (computes own block base from partial[]) +
// alone-node detection (deg==0). Requires nparts <= 64.
__global__ __launch_bounds__(256) void scan_final_kernel(const int* __restrict__ deg,
                                                         const int* __restrict__ partial,
                                                         int* __restrict__ row_off,
                                                         int* __restrict__ alone_list,
                                                         int* __restrict__ alone_count, int n) {
    __shared__ int wsum[4];
    __shared__ int sbase;
    int bid = blockIdx.x;
    int t = threadIdx.x, lane = t & 63, wid = t >> 6;
    if (wid == 0) {
        int v = (lane < bid) ? partial[lane] : 0;
        #pragma unroll
        for (int off = 1; off < 64; off <<= 1) v += __shfl_xor(v, off, 64);
        if (lane == 0) sbase = v;
    }
    int base = bid * 1024;
    int i0 = base + t * 4;
    int v0 = (i0 + 0 < n) ? deg[i0 + 0] : 0;
    int v1 = (i0 + 1 < n) ? deg[i0 + 1] : 0;
    int v2 = (i0 + 2 < n) ? deg[i0 + 2] : 0;
    int v3 = (i0 + 3 < n) ? deg[i0 + 3] : 0;
    int s = v0 + v1 + v2 + v3;
    int x = s;
    #pragma unroll
    for (int off = 1; off < 64; off <<= 1) {
        int y = __shfl_up(x, off, 64);
        if (lane >= off) x += y;
    }
    if (lane == 63) wsum[wid] = x;
    __syncthreads();
    int wbase = 0;
    #pragma unroll
    for (int w = 0; w < 4; ++w) { int ws = wsum[w]; if (w < wid) wbase += ws; }
    int p = sbase + wbase + x - s;
    if (i0 + 0 <= n) row_off[i0 + 0] = p;
    p += v0;
    if (i0 + 1 <= n) row_off[i0 + 1] = p;
    p += v1;
    if (i0 + 2 <= n) row_off[i0 + 2] = p;
    p += v2;
    if (i0 + 3 <= n) row_off[i0 + 3] = p;
    if (i0 + 0 < n && v0 == 0) { int q = atomicAdd(alone_count, 1); if (q < ALONE_CAP) alone_list[q] = i0; }
    if (i0 + 1 < n && v1 == 0) { int q = atomicAdd(alone_count, 1); if (q < ALONE_CAP) alone_list[q] = i0 + 1; }
    if (i0 + 2 < n && v2 == 0) { int q = atomicAdd(alone_count, 1); if (q < ALONE_CAP) alone_list[q] = i0 + 2; }
    if (i0 + 3 < n && v3 == 0) { int q = atomicAdd(alone_count, 1); if (q < ALONE_CAP) alone_list[q] = i0 + 3; }
}

// edges packed as uint: src | (ety << 16). Valid: N_ENTS=50000<2^16, N_RELS=200.
__global__ __launch_bounds__(256) void scatter_kernel(
    const int* __restrict__ src, const int* __restrict__ dst,
    const int* __restrict__ ety, const int* __restrict__ row_off,
    int* __restrict__ cursor, unsigned* __restrict__ edges, int e) {
    int i = blockIdx.x * 256 + threadIdx.x;
    if (i < e) {
        int v = dst[i];
        int pos = row_off[v] + atomicAdd(&cursor[v], 1);
        edges[pos] = (unsigned)src[i] | ((unsigned)ety[i] << 16);
    }
}

// ------------------------------------------------------- per-layer kernels
// S[v] = norm[v] * sum_e (h[src]+rel[et]); emitted interleaved hi/lo (Ssp).
// h gathered from PURE-BF16 table hb (256B/row -- halves L2-miss bytes, the
// R11-measured bottleneck at ~3.3 TB/s miss BW; confirmed R12). Sum fp32;
// rel fp32 (L2-hot). Masked 8-wide loop.
__global__ __launch_bounds__(256) void agg_kernel(
    const ushort* __restrict__ hb, const float* __restrict__ rel,
    const float* __restrict__ norm, const int* __restrict__ row_off,
    const unsigned* __restrict__ edges, unsigned* __restrict__ Ssp, int n) {
    int wave = threadIdx.x >> 6, lane = threadIdx.x & 63;
    int v = blockIdx.x * 4 + wave;
    if (v >= n) return;
    int s0 = row_off[v], s1 = row_off[v + 1];
    float nm = norm[v];
    int half = lane >> 5;
    int c4 = (lane & 31) * 4;
    float4 acc = make_float4(0.f, 0.f, 0.f, 0.f);
    const int last = s1 - 1;
    for (int e = s0; e < s1; e += 8) {
        const int i0 = e + half;
        const int i1 = e + 2 + half;
        const int i2 = e + 4 + half;
        const int i3 = e + 6 + half;
        unsigned q0 = edges[i0 < s1 ? i0 : last];
        unsigned q1 = edges[i1 < s1 ? i1 : last];
        unsigned q2 = edges[i2 < s1 ? i2 : last];
        unsigned q3 = edges[i3 < s1 ? i3 : last];
        const float m0 = (i0 < s1) ? 1.f : 0.f;
        const float m1 = (i1 < s1) ? 1.f : 0.f;
        const float m2 = (i2 < s1) ? 1.f : 0.f;
        const float m3 = (i3 < s1) ? 1.f : 0.f;
        ushort4 u0 = *(const ushort4*)&hb[(size_t)(q0 & 0xFFFFu) * 128 + c4];
        ushort4 u1 = *(const ushort4*)&hb[(size_t)(q1 & 0xFFFFu) * 128 + c4];
        ushort4 u2 = *(const ushort4*)&hb[(size_t)(q2 & 0xFFFFu) * 128 + c4];
        ushort4 u3 = *(const ushort4*)&hb[(size_t)(q3 & 0xFFFFu) * 128 + c4];
        float4 r0 = *(const float4*)&rel[(size_t)(q0 >> 16) * 128 + c4];
        float4 r1 = *(const float4*)&rel[(size_t)(q1 >> 16) * 128 + c4];
        float4 r2 = *(const float4*)&rel[(size_t)(q2 >> 16) * 128 + c4];
        float4 r3 = *(const float4*)&rel[(size_t)(q3 >> 16) * 128 + c4];
        acc.x = fmaf(m0, bf2f(u0.x) + r0.x, acc.x);
        acc.y = fmaf(m0, bf2f(u0.y) + r0.y, acc.y);
        acc.z = fmaf(m0, bf2f(u0.z) + r0.z, acc.z);
        acc.w = fmaf(m0, bf2f(u0.w) + r0.w, acc.w);
        acc.x = fmaf(m1, bf2f(u1.x) + r1.x, acc.x);
        acc.y = fmaf(m1, bf2f(u1.y) + r1.y, acc.y);
        acc.z = fmaf(m1, bf2f(u1.z) + r1.z, acc.z);
        acc.w = fmaf(m1, bf2f(u1.w) + r1.w, acc.w);
        acc.x = fmaf(m2, bf2f(u2.x) + r2.x, acc.x);
        acc.y = fmaf(m2, bf2f(u2.y) + r2.y, acc.y);
        acc.z = fmaf(m2, bf2f(u2.z) + r2.z, acc.z);
        acc.w = fmaf(m2, bf2f(u2.w) + r2.w, acc.w);
        acc.x = fmaf(m3, bf2f(u3.x) + r3.x, acc.x);
        acc.y = fmaf(m3, bf2f(u3.y) + r3.y, acc.y);
        acc.z = fmaf(m3, bf2f(u3.z) + r3.z, acc.z);
        acc.w = fmaf(m3, bf2f(u3.w) + r3.w, acc.w);
    }
    acc.x += __shfl_xor(acc.x, 32, 64);
    acc.y += __shfl_xor(acc.y, 32, 64);
    acc.z += __shfl_xor(acc.z, 32, 64);
    acc.w += __shfl_xor(acc.w, 32, 64);
    if (half == 0) {
        uint4 w;
        w.x = packsplit(acc.x * nm); w.y = packsplit(acc.y * nm);
        w.z = packsplit(acc.z * nm); w.w = packsplit(acc.w * nm);
        *(uint4*)&Ssp[(size_t)v * 128 + c4] = w;
    }
}

// out = leaky(S@Wn + H@Wl) via bf16-split MFMA (3 products).
// Block = 256 thr = 4 waves; wave tile 16 rows x 128 cols; grid ceil(n/64).
// R8 structure (proven): 64KB LDS holds one full matrix; stage Wn -> steps
// 0-3 barrier-free -> barrier -> stage Wl + hoist H (overlapped) -> barrier
// -> steps 4-7 barrier-free. 2 latency exposures, 3 barriers.
// R13: h1 is stored PLANAR (hi plane Ph + lo plane Pl, bf16 each):
//  - HMODE=0: H rows = raw fp32 (ent), split in regs (layer 0).
//  - HMODE=1: H rows = planar hi/lo (Ph1/Pl1); fragments are direct 16B
//    loads, zero unpack VALU (layer 1).
// Epilogue writes out (fp32) or Ph+Pl (25.6MB total -- R12's extra 12.8MB
// Ob16 write eliminated; agg-L1 gathers Ph directly).
// Alias-safe: each wave reads/writes only its own 16 rows.
template <int HMODE>
__global__ __launch_bounds__(256, 2) void gemm_mfma_kernel(
    const unsigned* __restrict__ Ssp,
    const unsigned* __restrict__ Hf,   // HMODE=0: fp32 rows
    const ushort* __restrict__ Hh,     // HMODE=1: hi plane
    const ushort* __restrict__ Hl,     // HMODE=1: lo plane
    const ushort* __restrict__ Wnh, const ushort* __restrict__ Wnl,
    const ushort* __restrict__ Wlh, const ushort* __restrict__ Wll,
    float* __restrict__ out, ushort* Ph, ushort* Pl, int n) {
    __shared__ ushort ldsB[4][2][4096];  // [kc][plane hi/lo][8KB] = 64KB

    const int tid = threadIdx.x;
    const int wave = tid >> 6, lane = tid & 63;
    const int quad = lane >> 4, l16 = lane & 15;
    const int row_base = blockIdx.x * 64 + wave * 16;

    int r0c = row_base + l16;
    if (r0c > n - 1) r0c = n - 1;
    const size_t arow = (size_t)r0c * 128;
    const int q8 = quad * 8;

    ffrag acc[8];
    #pragma unroll
    for (int ct = 0; ct < 8; ++ct) acc[ct] = (ffrag)0.f;

    // Stage one full matrix (4 kc-slices, hi+lo) into the 64KB buffer.
    // 16 named loads then 16 ds_writes (16-wide MLP, no spill-prone arrays).
#define STAGE_MAT(PH, PL)                                                        \
    {                                                                            \
        uint4 t00 = *(const uint4*)((PH) + 0 * 4096 + tid * 8);                  \
        uint4 t01 = *(const uint4*)((PH) + 0 * 4096 + 2048 + tid * 8);           \
        uint4 t02 = *(const uint4*)((PL) + 0 * 4096 + tid * 8);                  \
        uint4 t03 = *(const uint4*)((PL) + 0 * 4096 + 2048 + tid * 8);           \
        uint4 t10 = *(const uint4*)((PH) + 1 * 4096 + tid * 8);                  \
        uint4 t11 = *(const uint4*)((PH) + 1 * 4096 + 2048 + tid * 8);           \
        uint4 t12 = *(const uint4*)((PL) + 1 * 4096 + tid * 8);                  \
        uint4 t13 = *(const uint4*)((PL) + 1 * 4096 + 2048 + tid * 8);           \
        uint4 t20 = *(const uint4*)((PH) + 2 * 4096 + tid * 8);                  \
        uint4 t21 = *(const uint4*)((PH) + 2 * 4096 + 2048 + tid * 8);           \
        uint4 t22 = *(const uint4*)((PL) + 2 * 4096 + tid * 8);                  \
        uint4 t23 = *(const uint4*)((PL) + 2 * 4096 + 2048 + tid * 8);           \
        uint4 t30 = *(const uint4*)((PH) + 3 * 4096 + tid * 8);                  \
        uint4 t31 = *(const uint4*)((PH) + 3 * 4096 + 2048 + tid * 8);           \
        uint4 t32 = *(const uint4*)((PL) + 3 * 4096 + tid * 8);                  \
        uint4 t33 = *(const uint4*)((PL) + 3 * 4096 + 2048 + tid * 8);           \
        *(uint4*)&ldsB[0][0][tid * 8] = t00;                                     \
        *(uint4*)&ldsB[0][0][2048 + tid * 8] = t01;                              \
        *(uint4*)&ldsB[0][1][tid * 8] = t02;                                     \
        *(uint4*)&ldsB[0][1][2048 + tid * 8] = t03;                              \
        *(uint4*)&ldsB[1][0][tid * 8] = t10;                                     \
        *(uint4*)&ldsB[1][0][2048 + tid * 8] = t11;                              \
        *(uint4*)&ldsB[1][1][tid * 8] = t12;                                     \
        *(uint4*)&ldsB[1][1][2048 + tid * 8] = t13;                              \
        *(uint4*)&ldsB[2][0][tid * 8] = t20;                                     \
        *(uint4*)&ldsB[2][0][2048 + tid * 8] = t21;                              \
        *(uint4*)&ldsB[2][1][tid * 8] = t22;                                     \
        *(uint4*)&ldsB[2][1][2048 + tid * 8] = t23;                              \
        *(uint4*)&ldsB[3][0][tid * 8] = t30;                                     \
        *(uint4*)&ldsB[3][0][2048 + tid * 8] = t31;                              \
        *(uint4*)&ldsB[3][1][tid * 8] = t32;                                     \
        *(uint4*)&ldsB[3][1][2048 + tid * 8] = t33;                              \
    }

#define GREADB(KC)                                                               \
        bfrag bh[8], bl[8];                                                      \
        _Pragma("unroll")                                                        \
        for (int ct = 0; ct < 8; ++ct) {                                         \
            bh[ct] = *(const bfrag*)&ldsB[KC][0][ct * 512 + lane * 8];           \
            bl[ct] = *(const bfrag*)&ldsB[KC][1][ct * 512 + lane * 8];           \
        }

#define GMFMA3                                                                   \
        _Pragma("unroll")                                                        \
        for (int ct = 0; ct < 8; ++ct)                                           \
            acc[ct] = __builtin_amdgcn_mfma_f32_16x16x32_bf16(ah, bh[ct], acc[ct], 0, 0, 0); \
        _Pragma("unroll")                                                        \
        for (int ct = 0; ct < 8; ++ct)                                           \
            acc[ct] = __builtin_amdgcn_mfma_f32_16x16x32_bf16(ah, bl[ct], acc[ct], 0, 0, 0); \
        _Pragma("unroll")                                                        \
        for (int ct = 0; ct < 8; ++ct)                                           \
            acc[ct] = __builtin_amdgcn_mfma_f32_16x16x32_bf16(al, bh[ct], acc[ct], 0, 0, 0);

    // K-step, A = interleaved split words (Ssp)
#define GSTEP(KC, A0, A1)                                                        \
    {                                                                            \
        GREADB(KC)                                                               \
        bfrag ah, al;                                                            \
        _Pragma("unroll")                                                        \
        for (int j = 0; j < 4; ++j) {                                            \
            unsigned u0 = ((const unsigned*)&(A0))[j];                           \
            unsigned u1 = ((const unsigned*)&(A1))[j];                           \
            ah[j]     = (short)(u0 >> 16); al[j]     = (short)(u0 & 0xFFFFu);    \
            ah[j + 4] = (short)(u1 >> 16); al[j + 4] = (short)(u1 & 0xFFFFu);    \
        }                                                                        \
        GMFMA3                                                                   \
    }

    // K-step, A = fp32 bits (split in regs; identical math to packsplit)
#define GSTEP_F(KC, A0, A1)                                                      \
    {                                                                            \
        GREADB(KC)                                                               \
        bfrag ah, al;                                                            \
        _Pragma("unroll")                                                        \
        for (int j = 0; j < 4; ++j) {                                            \
            float fa = __uint_as_float(((const unsigned*)&(A0))[j]);             \
            float fb = __uint_as_float(((const unsigned*)&(A1))[j]);             \
            unsigned short ha = rne16(fa);                                       \
            unsigned short hb = rne16(fb);                                       \
            ah[j]     = (short)ha; al[j]     = (short)rne16(fa - bf2f(ha));      \
            ah[j + 4] = (short)hb; al[j + 4] = (short)rne16(fb - bf2f(hb));      \
        }                                                                        \
        GMFMA3                                                                   \
    }

    // K-step, A = planar bfrag pair (zero unpack)
#define GSTEP_P(KC, AH, AL)                                                      \
    {                                                                            \
        GREADB(KC)                                                               \
        bfrag ah = (AH);                                                         \
        bfrag al = (AL);                                                         \
        GMFMA3                                                                   \
    }

    // ---- prologue: S-half A hoist (8 named uint4) + stage Wn; one drain
    uint4 a00 = *(const uint4*)(Ssp + arow + 0 * 32 + q8);
    uint4 a01 = *(const uint4*)(Ssp + arow + 0 * 32 + q8 + 4);
    uint4 a10 = *(const uint4*)(Ssp + arow + 1 * 32 + q8);
    uint4 a11 = *(const uint4*)(Ssp + arow + 1 * 32 + q8 + 4);
    uint4 a20 = *(const uint4*)(Ssp + arow + 2 * 32 + q8);
    uint4 a21 = *(const uint4*)(Ssp + arow + 2 * 32 + q8 + 4);
    uint4 a30 = *(const uint4*)(Ssp + arow + 3 * 32 + q8);
    uint4 a31 = *(const uint4*)(Ssp + arow + 3 * 32 + q8 + 4);
    STAGE_MAT(Wnh, Wnl)
    __syncthreads();  // barrier 1: Wn staged (drains A hoist too)

    GSTEP(0, a00, a01)
    GSTEP(1, a10, a11)
    GSTEP(2, a20, a21)
    GSTEP(3, a30, a31)

    __syncthreads();  // barrier 2: all Wn reads complete

    // ---- midpoint: H-half A hoist + stage Wl; latencies overlap, one drain
    if (HMODE == 0) {
        uint4 a40 = *(const uint4*)(Hf + arow + 0 * 32 + q8);
        uint4 a41 = *(const uint4*)(Hf + arow + 0 * 32 + q8 + 4);
        uint4 a50 = *(const uint4*)(Hf + arow + 1 * 32 + q8);
        uint4 a51 = *(const uint4*)(Hf + arow + 1 * 32 + q8 + 4);
        uint4 a60 = *(const uint4*)(Hf + arow + 2 * 32 + q8);
        uint4 a61 = *(const uint4*)(Hf + arow + 2 * 32 + q8 + 4);
        uint4 a70 = *(const uint4*)(Hf + arow + 3 * 32 + q8);
        uint4 a71 = *(const uint4*)(Hf + arow + 3 * 32 + q8 + 4);
        STAGE_MAT(Wlh, Wll)
        __syncthreads();  // barrier 3: Wl staged (drains H hoist too)
        GSTEP_F(0, a40, a41)
        GSTEP_F(1, a50, a51)
        GSTEP_F(2, a60, a61)
        GSTEP_F(3, a70, a71)
    } else {
        bfrag hh0 = *(const bfrag*)(Hh + arow + 0 * 32 + q8);
        bfrag hh1 = *(const bfrag*)(Hh + arow + 1 * 32 + q8);
        bfrag hh2 = *(const bfrag*)(Hh + arow + 2 * 32 + q8);
        bfrag hh3 = *(const bfrag*)(Hh + arow + 3 * 32 + q8);
        bfrag hl0 = *(const bfrag*)(Hl + arow + 0 * 32 + q8);
        bfrag hl1 = *(const bfrag*)(Hl + arow + 1 * 32 + q8);
        bfrag hl2 = *(const bfrag*)(Hl + arow + 2 * 32 + q8);
        bfrag hl3 = *(const bfrag*)(Hl + arow + 3 * 32 + q8);
        STAGE_MAT(Wlh, Wll)
        __syncthreads();  // barrier 3: Wl staged (drains H hoist too)
        GSTEP_P(0, hh0, hl0)
        GSTEP_P(1, hh1, hl1)
        GSTEP_P(2, hh2, hl2)
        GSTEP_P(3, hh3, hl3)
    }
#undef GSTEP
#undef GSTEP_F
#undef GSTEP_P
#undef GREADB
#undef GMFMA3
#undef STAGE_MAT

    #pragma unroll
    for (int ct = 0; ct < 8; ++ct) {
        #pragma unroll
        for (int rg = 0; rg < 4; ++rg) {
            int r = row_base + quad * 4 + rg;
            if (r < n) {
                int c = ct * 16 + l16;
                float v = acc[ct][rg];
                v = v >= 0.f ? v : v * SLOPE;
                if (out) out[(size_t)r * 128 + c] = v;
                if (Ph) {
                    unsigned short hi = rne16(v);
                    Ph[(size_t)r * 128 + c] = hi;
                    Pl[(size_t)r * 128 + c] = rne16(v - bf2f(hi));
                }
            }
        }
    }
}

// Alone nodes: o = leaky(hrow @ Wa).
// Layer 0 (by_node=1): hrow = ent[v]; writes Ph/Pl (h1 planar) + asave fp32.
// Layer 1 (by_node=0): hrow = asave[i]; writes out fp32.
__global__ __launch_bounds__(128) void fixup_kernel(
    const float* __restrict__ Hrows, int by_node,
    const float* __restrict__ Wa,
    const int* __restrict__ alone_list, const int* __restrict__ alone_count,
    float* out, ushort* Ph, ushort* Pl, float* asave) {
    int cnt = *alone_count;
    if (cnt > ALONE_CAP) cnt = ALONE_CAP;
    int t = threadIdx.x;
    for (int i = blockIdx.x; i < cnt; i += gridDim.x) {
        int v = alone_list[i];
        const float* hrow = Hrows + (size_t)(by_node ? v : i) * 128;
        float acc = 0.f;
        for (int k = 0; k < 128; ++k)
            acc += hrow[k] * Wa[k * 128 + t];
        float o = acc >= 0.f ? acc : acc * SLOPE;
        if (out) out[(size_t)v * 128 + t] = o;
        if (Ph) {
            unsigned short hi = rne16(o);
            Ph[(size_t)v * 128 + t] = hi;
            Pl[(size_t)v * 128 + t] = rne16(o - bf2f(hi));
        }
        if (asave) asave[(size_t)i * 128 + t] = o;
    }
}

extern "C" void kernel_launch(void* const* d_in, const int* in_sizes, int n_in,
                              void* d_out, int out_size, void* d_ws, size_t ws_size,
                              hipStream_t stream) {
    const float* ent  = (const float*)d_in[0];
    const float* rel  = (const float*)d_in[1];
    const float* norm = (const float*)d_in[2];
    const float* Wn   = (const float*)d_in[3];
    const float* Wl   = (const float*)d_in[4];
    const float* Wa   = (const float*)d_in[5];
    const int*   src  = (const int*)d_in[6];
    const int*   dst  = (const int*)d_in[7];
    const int*   ety  = (const int*)d_in[8];
    float* out = (float*)d_out;

    const int n = in_sizes[2];   // 50000
    const int e = in_sizes[7];   // 500000

    // workspace layout
    char* ws = (char*)d_ws;
    int* deg         = (int*)ws;          // n
    int* cursor      = deg + n;           // n
    int* alone_count = cursor + n;        // 1
    size_t zbytes = (size_t)(2 * n + 1) * sizeof(int);
    size_t p = (zbytes + 255) & ~(size_t)255;
    int* row_off = (int*)(ws + p);        // n+1
    p += (((size_t)(n + 1) * 4) + 255) & ~(size_t)255;
    int* partial = (int*)(ws + p);        // <=64
    p += 256;
    int* alone_list = (int*)(ws + p);     // ALONE_CAP
    p += (((size_t)ALONE_CAP * 4) + 255) & ~(size_t)255;
    float* asave = (float*)(ws + p);      // ALONE_CAP*128 f32 (1 MB)
    p += (((size_t)ALONE_CAP * 128 * 4) + 255) & ~(size_t)255;
    unsigned* edges = (unsigned*)(ws + p);// e packed (2 MB)
    p += (((size_t)e * 4) + 255) & ~(size_t)255;
    unsigned* Ssp = (unsigned*)(ws + p);  // n*128 interleaved split (25.6 MB)
    p += (((size_t)n * 128 * 4) + 255) & ~(size_t)255;
    ushort* Eb0 = (ushort*)(ws + p);      // ent bf16 table (12.8 MB)
    p += (((size_t)n * 128 * 2) + 255) & ~(size_t)255;
    ushort* Ph1 = (ushort*)(ws + p);      // h1 hi plane (12.8 MB)
    p += (((size_t)n * 128 * 2) + 255) & ~(size_t)255;
    ushort* Pl1 = (ushort*)(ws + p);      // h1 lo plane (12.8 MB)
    p += (((size_t)n * 128 * 2) + 255) & ~(size_t)255;
    ushort* packW = (ushort*)(ws + p);    // 4 mats x (hi16K + lo16K) (256 KB)
    p += 4 * 32768 * 2;

    const int eb = (e + 255) / 256;             // 1954
    const int cb = (n * 16 + 255) / 256;        // 3125 (uint4 = 8 elems)
    const int nparts = (n + 1023) / 1024;       // 49 (<=64 required)
    const int gb = (n + 63) / 64;               // 782
    const int ab = (n + 3) / 4;                 // 12500

    hipMemsetAsync(ws, 0, zbytes, stream);
    prep_kernel<<<eb + cb + 32, 256, 0, stream>>>(dst, deg, e, eb,
                                                  ent, Eb0, n * 16, cb,
                                                  Wn, Wl, packW);
    scan_partial_kernel<<<nparts, 256, 0, stream>>>(deg, partial, n);
    scan_final_kernel<<<nparts, 256, 0, stream>>>(deg, partial, row_off,
                                                  alone_list, alone_count, n);
    scatter_kernel<<<eb, 256, 0, stream>>>(src, dst, ety, row_off, cursor, edges, e);

    // layer 0: agg gathers bf16 ent (Eb0); gemm H = ent fp32 (in-reg split);
    // outputs h1 PLANAR: Ph1 (hi, also agg-1's gather table) + Pl1 (lo)
    agg_kernel<<<ab, 256, 0, stream>>>(Eb0, rel, norm, row_off, edges, Ssp, n);
    gemm_mfma_kernel<0><<<gb, 256, 0, stream>>>(Ssp, (const unsigned*)ent,
                                                nullptr, nullptr,
                                                packW, packW + 16384,
                                                packW + 32768, packW + 49152,
                                                nullptr, Ph1, Pl1, n);
    fixup_kernel<<<16, 128, 0, stream>>>(ent, 1, Wa, alone_list, alone_count,
                                         nullptr, Ph1, Pl1, asave);

    // layer 1: agg gathers Ph1 (bf16 hi); gemm H = planar Ph1/Pl1; out fp32
    agg_kernel<<<ab, 256, 0, stream>>>(Ph1, rel, norm, row_off, edges, Ssp, n);
    gemm_mfma_kernel<1><<<gb, 256, 0, stream>>>(Ssp, nullptr,
                                                Ph1, Pl1,
                                                packW + 65536, packW + 81920,
                                                packW + 98304, packW + 114688,
                                                out, nullptr, nullptr, n);
    fixup_kernel<<<16, 128, 0, stream>>>(asave, 0, Wa + 16384, alone_list, alone_count,
                                         out, nullptr, nullptr, nullptr);
}